// Round 5
// baseline (5415.772 us; speedup 1.0000x reference)
//
#include <hip/hip_runtime.h>
#include <hip/hip_cooperative_groups.h>

namespace cg = cooperative_groups;

#define NS_ 26
#define NCLS_ 97

typedef short bf16x8 __attribute__((ext_vector_type(8)));
typedef float f32x4 __attribute__((ext_vector_type(4)));

__device__ __forceinline__ unsigned short f2bf(float f) {
  union { float f; unsigned u; } v; v.f = f;
  unsigned r = v.u + 0x7fffu + ((v.u >> 16) & 1u);
  return (unsigned short)(r >> 16);
}
__device__ __forceinline__ float bf2f(unsigned short h) {
  union { unsigned u; float f; } v; v.u = ((unsigned)h) << 16;
  return v.f;
}
__device__ __forceinline__ float sigm_f(float x) { return 1.f / (1.f + __expf(-x)); }
__device__ __forceinline__ float tanh_f(float x) { return 1.f - 2.f / (1.f + __expf(2.f * x)); }

__device__ __forceinline__ void gl_lds16(const void* g, void* l) {
  __builtin_amdgcn_global_load_lds(
      (const __attribute__((address_space(1))) unsigned int*)g,
      (__attribute__((address_space(3))) unsigned int*)l, 16, 0, 0);
}

// ============ tiled 128x128 GEMM (prologue) ============
template <bool OUTF>
__global__ __launch_bounds__(256) void gemm_tiled_k(
    const unsigned short* __restrict__ Ag, const unsigned short* __restrict__ Bg,
    const float* __restrict__ bias, float* __restrict__ outF,
    unsigned short* __restrict__ outB, int K, long ldo, int Nvalid) {
  __shared__ unsigned short As[128 * 64];
  __shared__ unsigned short Bs[128 * 64];
  const int tid = threadIdx.x;
  const int w = tid >> 6, l = tid & 63;
  const int l15 = l & 15, lq = l >> 4;
  const int wm = w >> 1, wn = w & 1;
  const long rowBase = (long)blockIdx.y * 128;
  const long colBase = (long)blockIdx.x * 128;
  const int lrow = l >> 3, ps_st = l & 7;
  f32x4 acc[4][4] = {};
  for (int kt = 0; kt < K; kt += 64) {
#pragma unroll
    for (int i = 0; i < 4; ++i) {
      const int row = i * 32 + w * 8 + lrow;
      const int ls = ps_st ^ (row & 7);
      gl_lds16(Ag + (rowBase + row) * K + kt + ls * 8, As + i * 2048 + w * 512);
      gl_lds16(Bg + (colBase + row) * K + kt + ls * 8, Bs + i * 2048 + w * 512);
    }
    __syncthreads();
#pragma unroll
    for (int kh = 0; kh < 2; ++kh) {
      bf16x8 af[4], bfr[4];
#pragma unroll
      for (int mi = 0; mi < 4; ++mi) {
        const int row = wm * 64 + mi * 16 + l15;
        const int ps = (kh * 4 + lq) ^ (row & 7);
        af[mi] = *(const bf16x8*)(As + row * 64 + ps * 8);
      }
#pragma unroll
      for (int ni = 0; ni < 4; ++ni) {
        const int row = wn * 64 + ni * 16 + l15;
        const int ps = (kh * 4 + lq) ^ (row & 7);
        bfr[ni] = *(const bf16x8*)(Bs + row * 64 + ps * 8);
      }
#pragma unroll
      for (int mi = 0; mi < 4; ++mi)
#pragma unroll
        for (int ni = 0; ni < 4; ++ni)
          acc[mi][ni] = __builtin_amdgcn_mfma_f32_16x16x32_bf16(af[mi], bfr[ni], acc[mi][ni], 0, 0, 0);
    }
    __syncthreads();
  }
#pragma unroll
  for (int mi = 0; mi < 4; ++mi)
#pragma unroll
    for (int ni = 0; ni < 4; ++ni) {
      const long gcol = colBase + wn * 64 + ni * 16 + l15;
      if (gcol >= Nvalid) continue;
      const float bv = bias ? bias[gcol] : 0.f;
#pragma unroll
      for (int r = 0; r < 4; ++r) {
        const long grow = rowBase + wm * 64 + mi * 16 + lq * 4 + r;
        const float v = acc[mi][ni][r] + bv;
        if (OUTF) outF[grow * ldo + gcol] = v;
        else      outB[grow * ldo + gcol] = f2bf(v);
      }
    }
}

// ============ persistent cooperative scan kernel (grid = 256 blocks) ============
struct CoopArgs {
  const unsigned short* Hproj;   // [B,64,512] bf16
  const unsigned short* bH;      // [B,64,512] bf16
  const unsigned short* WA;      // [2560,512] bf16
  const unsigned short* Wfz;     // [1024,512] bf16 (Wf1 | Wz-left)
  const unsigned short* FZpre;   // [B*NS,1024] bf16
  const unsigned short* WihE;    // [2048,768] bf16
  const unsigned short* embb;    // [B,NS,256] bf16
  const unsigned short* Wgenb;   // [128,512] bf16
  const float* biasA;            // [2560]
  const float* w_score;          // [512]
  const float* bf1;              // [512]
  const float* b_gen;            // [97]
  float* hpgh;                   // [512,2560]
  float* out_attn;               // [B,64,NS]
  float* out_char;               // [B,NS,512]
  float* out_hid;                // [B,NS,512]
  float* out_probs;              // [B*NS,97]
  float* cbuf;                   // [B,512]
  unsigned short* ctx;           // [B,512] bf16
  unsigned short* Ichar;         // [B,512] bf16
  unsigned short* hbuf;          // 2x [B,512] bf16
};

__global__ __launch_bounds__(256) void scan_coop_k(CoopArgs A) {
  cg::grid_group grid = cg::this_grid();
  __shared__ float smem[2688];   // [0..2176): phase scratch; [2176..2688): ws_s
  float* ws_s = smem + 2176;
  const int tid = threadIdx.x;
  const int w = tid >> 6, l = tid & 63, l15 = l & 15, lq = l >> 4;
  const int bx = blockIdx.x;

  ws_s[tid] = A.w_score[tid];
  ws_s[tid + 256] = A.w_score[tid + 256];

  for (int s = 0; s < NS_; ++s) {
    const unsigned short* hrd = A.hbuf + (s & 1) * 262144;
    unsigned short* hwr = A.hbuf + ((s + 1) & 1) * 262144;

    // ---- P1: hpgh = h @ [W_h2h|W_hh]^T + biasA  (320 units of 64x64) ----
    for (int u = bx; u < 320; u += 256) {
      const int jt = u % 40, bt = u / 40;
      const int nbase = jt * 64;
      const long mrow = (long)bt * 64 + w * 16 + l15;
      f32x4 acc[4] = {};
      for (int kt = 0; kt < 512; kt += 64) {
        const int k0 = kt + lq * 8, k1 = k0 + 32;
        const bf16x8 a0 = *(const bf16x8*)(hrd + mrow * 512 + k0);
        const bf16x8 a1 = *(const bf16x8*)(hrd + mrow * 512 + k1);
        bf16x8 b0[4], b1[4];
#pragma unroll
        for (int ni = 0; ni < 4; ++ni) {
          const long wr = nbase + ni * 16 + l15;
          b0[ni] = *(const bf16x8*)(A.WA + wr * 512 + k0);
          b1[ni] = *(const bf16x8*)(A.WA + wr * 512 + k1);
        }
#pragma unroll
        for (int ni = 0; ni < 4; ++ni) {
          acc[ni] = __builtin_amdgcn_mfma_f32_16x16x32_bf16(a0, b0[ni], acc[ni], 0, 0, 0);
          acc[ni] = __builtin_amdgcn_mfma_f32_16x16x32_bf16(a1, b1[ni], acc[ni], 0, 0, 0);
        }
      }
#pragma unroll
      for (int ni = 0; ni < 4; ++ni) {
        const int colg = nbase + ni * 16 + l15;
        const float bv = A.biasA[colg];
#pragma unroll
        for (int r = 0; r < 4; ++r) {
          const long rowg = (long)bt * 64 + w * 16 + lq * 4 + r;
          A.hpgh[rowg * 2560 + colg] = acc[ni][r] + bv;
        }
      }
    }
    grid.sync();

    // ---- P2: attention (2 batch rows per block) ----
    {
      float* hp_s = smem;
      float* e_s = smem + 512;
      for (int b = bx; b < 512; b += 256) {
        __syncthreads();
        hp_s[tid] = A.hpgh[(long)b * 2560 + tid];
        hp_s[tid + 256] = A.hpgh[(long)b * 2560 + tid + 256];
        __syncthreads();
#pragma unroll
        for (int tt = 0; tt < 16; ++tt) {
          const int t = w * 16 + tt;
          const bf16x8 hv = *(const bf16x8*)(A.Hproj + ((long)b * 64 + t) * 512 + l * 8);
          float acc = 0.f;
#pragma unroll
          for (int j = 0; j < 8; ++j)
            acc += tanh_f(bf2f((unsigned short)hv[j]) + hp_s[l * 8 + j]) * ws_s[l * 8 + j];
          acc += __shfl_xor(acc, 1);
          acc += __shfl_xor(acc, 2);
          acc += __shfl_xor(acc, 4);
          acc += __shfl_xor(acc, 8);
          acc += __shfl_xor(acc, 16);
          acc += __shfl_xor(acc, 32);
          if (l == 0) e_s[t] = acc;
        }
        __syncthreads();
        if (tid < 64) {
          const float e = e_s[tid];
          float m = e;
          for (int off = 32; off; off >>= 1) m = fmaxf(m, __shfl_xor(m, off));
          const float p = __expf(e - m);
          float sum = p;
          for (int off = 32; off; off >>= 1) sum += __shfl_xor(sum, off);
          const float al = p / sum;
          e_s[tid] = al;
          A.out_attn[((long)b * 64 + tid) * NS_ + s] = al;
        }
        __syncthreads();
        float c0 = 0.f, c1 = 0.f;
        const unsigned* bhp = (const unsigned*)(A.bH + (long)b * 64 * 512) + tid;
#pragma unroll 8
        for (int t = 0; t < 64; ++t) {
          const float al = e_s[t];
          const unsigned pv = bhp[(long)t * 256];
          c0 += al * bf2f((unsigned short)(pv & 0xffffu));
          c1 += al * bf2f((unsigned short)(pv >> 16));
        }
        ((unsigned*)A.ctx)[(long)b * 256 + tid] = (unsigned)f2bf(c0) | ((unsigned)f2bf(c1) << 16);
      }
    }
    grid.sync();

    // ---- P3: gated fusion (512 units: 16 rows x 32 cols; wave=(which,colhalf)) ----
    for (int u = bx; u < 512; u += 256) {
      const int jt = u & 15, bt = u >> 4;
      const int j0 = jt * 32, b0 = bt * 16;
      const int which = w >> 1, nh = w & 1;
      f32x4 acc = {};
      const long arow = b0 + l15;
      const long gw = (long)(which ? 512 : 0) + j0 + nh * 16 + l15;
      for (int kt = 0; kt < 512; kt += 64) {
        const int k0 = kt + lq * 8, k1 = k0 + 32;
        const bf16x8 a0 = *(const bf16x8*)(A.ctx + arow * 512 + k0);
        const bf16x8 a1 = *(const bf16x8*)(A.ctx + arow * 512 + k1);
        const bf16x8 w0 = *(const bf16x8*)(A.Wfz + gw * 512 + k0);
        const bf16x8 w1 = *(const bf16x8*)(A.Wfz + gw * 512 + k1);
        acc = __builtin_amdgcn_mfma_f32_16x16x32_bf16(a0, w0, acc, 0, 0, 0);
        acc = __builtin_amdgcn_mfma_f32_16x16x32_bf16(a1, w1, acc, 0, 0, 0);
      }
#pragma unroll
      for (int r = 0; r < 4; ++r)
        smem[which * 528 + (lq * 4 + r) * 33 + nh * 16 + l15] = acc[r];
      __syncthreads();
#pragma unroll
      for (int i = 0; i < 2; ++i) {
        const int e = tid + i * 256;
        const int r = e >> 5, c = e & 31;
        const long b = b0 + r;
        const int j = j0 + c;
        const float f1 = tanh_f(smem[r * 33 + c] + A.bf1[j]);
        const float zc = smem[528 + r * 33 + c];
        const long pr = (b * NS_ + s) * 1024;
        const float f2 = tanh_f(bf2f(A.FZpre[pr + j]));
        const float z = sigm_f(zc + bf2f(A.FZpre[pr + 512 + j]));
        const float I = z * f1 + (1.f - z) * f2;
        A.out_char[(b * NS_ + s) * 512 + j] = I;
        A.Ichar[b * 512 + j] = f2bf(I);
      }
      __syncthreads();
    }
    grid.sync();

    // ---- P4: gates GEMM + LSTM (512 units: 32 rows x 16 cols; wave=gate) ----
    for (int u = bx; u < 512; u += 256) {
      const int jt = u & 31, bt = u >> 5;
      const int j0 = jt * 16, b0 = bt * 32;
      const int g = w;
      f32x4 acc[2] = {};
      const long wrow = (long)g * 512 + j0 + l15;
      for (int kt = 0; kt < 768; kt += 64) {
        const int k0 = kt + lq * 8, k1 = k0 + 32;
        bf16x8 a0[2], a1[2];
#pragma unroll
        for (int mi = 0; mi < 2; ++mi) {
          const long ar = b0 + mi * 16 + l15;
          a0[mi] = (k0 < 512) ? *(const bf16x8*)(A.Ichar + ar * 512 + k0)
                              : *(const bf16x8*)(A.embb + (ar * NS_ + s) * 256 + (k0 - 512));
          a1[mi] = (k1 < 512) ? *(const bf16x8*)(A.Ichar + ar * 512 + k1)
                              : *(const bf16x8*)(A.embb + (ar * NS_ + s) * 256 + (k1 - 512));
        }
        const bf16x8 w0 = *(const bf16x8*)(A.WihE + wrow * 768 + k0);
        const bf16x8 w1 = *(const bf16x8*)(A.WihE + wrow * 768 + k1);
#pragma unroll
        for (int mi = 0; mi < 2; ++mi) {
          acc[mi] = __builtin_amdgcn_mfma_f32_16x16x32_bf16(a0[mi], w0, acc[mi], 0, 0, 0);
          acc[mi] = __builtin_amdgcn_mfma_f32_16x16x32_bf16(a1[mi], w1, acc[mi], 0, 0, 0);
        }
      }
#pragma unroll
      for (int mi = 0; mi < 2; ++mi)
#pragma unroll
        for (int r = 0; r < 4; ++r)
          smem[g * 544 + (mi * 16 + lq * 4 + r) * 17 + l15] = acc[mi][r];
      __syncthreads();
#pragma unroll
      for (int i = 0; i < 2; ++i) {
        const int e = tid + i * 256;
        const int r = e >> 4, c = e & 15;
        const long b = b0 + r;
        const int j = j0 + c;
        const float* ggh = A.hpgh + b * 2560 + 512;
        const float ig = sigm_f(smem[r * 17 + c] + ggh[j]);
        const float fg = sigm_f(smem[544 + r * 17 + c] + ggh[512 + j]);
        const float gg = tanh_f(smem[1088 + r * 17 + c] + ggh[1024 + j]);
        const float og = sigm_f(smem[1632 + r * 17 + c] + ggh[1536 + j]);
        const float cn = fg * A.cbuf[b * 512 + j] + ig * gg;
        A.cbuf[b * 512 + j] = cn;
        const float h = og * tanh_f(cn);
        A.out_hid[(b * NS_ + s) * 512 + j] = h;
        hwr[b * 512 + j] = f2bf(h);
      }
      __syncthreads();
    }
    grid.sync();
  }

  // ---- P5: probs = out_hid @ W_gen^T + b_gen (416 units of 64x64) ----
  for (int u = bx; u < 416; u += 256) {
    const int jt = u & 1, bt = u >> 1;
    const int nbase = jt * 64;
    const long mrow = (long)bt * 64 + w * 16 + l15;
    f32x4 acc[4] = {};
    for (int kt = 0; kt < 512; kt += 32) {
      const int k = kt + lq * 8;
      const float4 av0 = *(const float4*)(A.out_hid + mrow * 512 + k);
      const float4 av1 = *(const float4*)(A.out_hid + mrow * 512 + k + 4);
      bf16x8 a;
      a[0] = (short)f2bf(av0.x); a[1] = (short)f2bf(av0.y);
      a[2] = (short)f2bf(av0.z); a[3] = (short)f2bf(av0.w);
      a[4] = (short)f2bf(av1.x); a[5] = (short)f2bf(av1.y);
      a[6] = (short)f2bf(av1.z); a[7] = (short)f2bf(av1.w);
#pragma unroll
      for (int nb = 0; nb < 4; ++nb) {
        const bf16x8 b = *(const bf16x8*)(A.Wgenb + (long)(nbase + nb * 16 + l15) * 512 + k);
        acc[nb] = __builtin_amdgcn_mfma_f32_16x16x32_bf16(a, b, acc[nb], 0, 0, 0);
      }
    }
#pragma unroll
    for (int nb = 0; nb < 4; ++nb) {
      const int colg = nbase + nb * 16 + l15;
      if (colg >= NCLS_) continue;
      const float bv = A.b_gen[colg];
#pragma unroll
      for (int r = 0; r < 4; ++r) {
        const long rowg = (long)bt * 64 + w * 16 + lq * 4 + r;
        A.out_probs[rowg * NCLS_ + colg] = acc[nb][r] + bv;
      }
    }
  }
}

// ============ fallback per-step kernels (proven round-3 path) ============
__global__ __launch_bounds__(256) void gemm_hpgh_k(
    const unsigned short* __restrict__ h, const unsigned short* __restrict__ WA,
    const float* __restrict__ biasA, float* __restrict__ hpgh) {
  const int tid = threadIdx.x, w = tid >> 6, l = tid & 63, l15 = l & 15, lq = l >> 4;
  const long mrow = (long)blockIdx.y * 64 + w * 16 + l15;
  const int nbase = blockIdx.x * 64;
  f32x4 acc[4] = {};
  for (int kt = 0; kt < 512; kt += 64) {
    const int k0 = kt + lq * 8, k1 = k0 + 32;
    const bf16x8 a0 = *(const bf16x8*)(h + mrow * 512 + k0);
    const bf16x8 a1 = *(const bf16x8*)(h + mrow * 512 + k1);
    bf16x8 b0[4], b1[4];
#pragma unroll
    for (int nb = 0; nb < 4; ++nb) {
      const long wr = nbase + nb * 16 + l15;
      b0[nb] = *(const bf16x8*)(WA + wr * 512 + k0);
      b1[nb] = *(const bf16x8*)(WA + wr * 512 + k1);
    }
#pragma unroll
    for (int nb = 0; nb < 4; ++nb) {
      acc[nb] = __builtin_amdgcn_mfma_f32_16x16x32_bf16(a0, b0[nb], acc[nb], 0, 0, 0);
      acc[nb] = __builtin_amdgcn_mfma_f32_16x16x32_bf16(a1, b1[nb], acc[nb], 0, 0, 0);
    }
  }
#pragma unroll
  for (int nb = 0; nb < 4; ++nb) {
    const int colg = nbase + nb * 16 + l15;
    const float bv = biasA[colg];
#pragma unroll
    for (int r = 0; r < 4; ++r) {
      const long rowg = (long)blockIdx.y * 64 + w * 16 + lq * 4 + r;
      hpgh[rowg * 2560 + colg] = acc[nb][r] + bv;
    }
  }
}

__global__ __launch_bounds__(512) void attn_step_k(
    const unsigned short* __restrict__ Hproj, const unsigned short* __restrict__ bH,
    const float* __restrict__ hpgh, const float* __restrict__ w_score,
    float* __restrict__ attn_map, unsigned short* __restrict__ ctx, int s) {
  const int b = blockIdx.x, tid = threadIdx.x;
  __shared__ float hp_s[512], ws_s[512], e_s[64], csum[512];
  hp_s[tid] = hpgh[(long)b * 2560 + tid];
  ws_s[tid] = w_score[tid];
  __syncthreads();
  const int w = tid >> 6, l = tid & 63;
  const unsigned short* Hrow = Hproj + ((long)b * 64 + w * 8) * 512 + l * 8;
#pragma unroll
  for (int tt = 0; tt < 8; ++tt) {
    const bf16x8 hv = *(const bf16x8*)(Hrow + tt * 512);
    float acc = 0.f;
#pragma unroll
    for (int j = 0; j < 8; ++j) {
      const int h = l * 8 + j;
      acc += tanh_f(bf2f((unsigned short)hv[j]) + hp_s[h]) * ws_s[h];
    }
    acc += __shfl_xor(acc, 1);
    acc += __shfl_xor(acc, 2);
    acc += __shfl_xor(acc, 4);
    acc += __shfl_xor(acc, 8);
    acc += __shfl_xor(acc, 16);
    acc += __shfl_xor(acc, 32);
    if (l == 0) e_s[w * 8 + tt] = acc;
  }
  __syncthreads();
  if (tid < 64) {
    const float e = e_s[tid];
    float m = e;
    for (int off = 32; off; off >>= 1) m = fmaxf(m, __shfl_xor(m, off));
    const float p = __expf(e - m);
    float sum = p;
    for (int off = 32; off; off >>= 1) sum += __shfl_xor(sum, off);
    const float a = p / sum;
    e_s[tid] = a;
    attn_map[((long)b * 64 + tid) * NS_ + s] = a;
  }
  __syncthreads();
  const int half = tid >> 8, jj = tid & 255;
  float c0 = 0.f, c1 = 0.f;
  const unsigned* bhp = (const unsigned*)(bH + ((long)b * 64 + half * 32) * 512) + jj;
#pragma unroll 8
  for (int t = 0; t < 32; ++t) {
    const float a = e_s[half * 32 + t];
    const unsigned pv = bhp[(long)t * 256];
    c0 += a * bf2f((unsigned short)(pv & 0xffffu));
    c1 += a * bf2f((unsigned short)(pv >> 16));
  }
  if (half) { csum[jj * 2] = c0; csum[jj * 2 + 1] = c1; }
  __syncthreads();
  if (!half) {
    c0 += csum[jj * 2];
    c1 += csum[jj * 2 + 1];
    ((unsigned*)ctx)[(long)b * 256 + jj] = (unsigned)f2bf(c0) | ((unsigned)f2bf(c1) << 16);
  }
}

__global__ __launch_bounds__(512) void gated_fused_k(
    const unsigned short* __restrict__ ctx, const unsigned short* __restrict__ Wfz,
    const unsigned short* __restrict__ FZpre, const float* __restrict__ bf1,
    unsigned short* __restrict__ Ichar, float* __restrict__ Char_out, int s) {
  __shared__ float ls[2 * 64 * 65];
  const int tid = threadIdx.x, w = tid >> 6, l = tid & 63, l15 = l & 15, lq = l >> 4;
  const int b0 = blockIdx.y * 64, j0 = blockIdx.x * 64;
  const int mi2 = w & 1, nq = w >> 1;
  f32x4 acc[2][2] = {};
  for (int kt = 0; kt < 512; kt += 64) {
    const int k0 = kt + lq * 8, k1 = k0 + 32;
    bf16x8 a0[2], a1[2], bb0[2], bb1[2];
#pragma unroll
    for (int mi = 0; mi < 2; ++mi) {
      const long row = b0 + mi2 * 32 + mi * 16 + l15;
      a0[mi] = *(const bf16x8*)(ctx + row * 512 + k0);
      a1[mi] = *(const bf16x8*)(ctx + row * 512 + k1);
    }
#pragma unroll
    for (int ni = 0; ni < 2; ++ni) {
      const int wl = nq * 32 + ni * 16 + l15;
      const long gw = (wl < 64) ? (j0 + wl) : (512 + j0 + wl - 64);
      bb0[ni] = *(const bf16x8*)(Wfz + gw * 512 + k0);
      bb1[ni] = *(const bf16x8*)(Wfz + gw * 512 + k1);
    }
#pragma unroll
    for (int mi = 0; mi < 2; ++mi)
#pragma unroll
      for (int ni = 0; ni < 2; ++ni) {
        acc[mi][ni] = __builtin_amdgcn_mfma_f32_16x16x32_bf16(a0[mi], bb0[ni], acc[mi][ni], 0, 0, 0);
        acc[mi][ni] = __builtin_amdgcn_mfma_f32_16x16x32_bf16(a1[mi], bb1[ni], acc[mi][ni], 0, 0, 0);
      }
  }
  float* dst = ls + (nq >> 1) * (64 * 65);
#pragma unroll
  for (int mi = 0; mi < 2; ++mi)
#pragma unroll
    for (int ni = 0; ni < 2; ++ni)
#pragma unroll
      for (int r = 0; r < 4; ++r) {
        const int rl = mi2 * 32 + mi * 16 + lq * 4 + r;
        const int cl = (nq & 1) * 32 + ni * 16 + l15;
        dst[rl * 65 + cl] = acc[mi][ni][r];
      }
  __syncthreads();
#pragma unroll
  for (int i = 0; i < 8; ++i) {
    const int e = tid + i * 512;
    const int r = e >> 6, c = e & 63;
    const long b = b0 + r;
    const int j = j0 + c;
    const float f1 = tanh_f(ls[r * 65 + c] + bf1[j]);
    const float zc = ls[64 * 65 + r * 65 + c];
    const long pr = (b * NS_ + s) * 1024;
    const float f2 = tanh_f(bf2f(FZpre[pr + j]));
    const float z = sigm_f(zc + bf2f(FZpre[pr + 512 + j]));
    const float I = z * f1 + (1.f - z) * f2;
    Char_out[(b * NS_ + s) * 512 + j] = I;
    Ichar[b * 512 + j] = f2bf(I);
  }
}

__global__ __launch_bounds__(512) void gates_lstm_k(
    const unsigned short* __restrict__ Ichar, const unsigned short* __restrict__ embb,
    const unsigned short* __restrict__ WihE, const float* __restrict__ hpgh,
    float* __restrict__ cbuf, float* __restrict__ hid_out,
    unsigned short* __restrict__ hwr, int s) {
  __shared__ float gs[4 * 32 * 65];
  const int tid = threadIdx.x, w = tid >> 6, l = tid & 63, l15 = l & 15, lq = l >> 4;
  const int b0 = blockIdx.y * 32, j0 = blockIdx.x * 64;
  const int g = w & 3, mi = w >> 2;
  const long arow = b0 + mi * 16 + l15;
  f32x4 acc[4] = {};
  for (int kt = 0; kt < 768; kt += 64) {
    const int k0 = kt + lq * 8, k1 = k0 + 32;
    bf16x8 a0, a1, b0r[4], b1r[4];
    a0 = (k0 < 512) ? *(const bf16x8*)(Ichar + arow * 512 + k0)
                    : *(const bf16x8*)(embb + (arow * NS_ + s) * 256 + (k0 - 512));
    a1 = (k1 < 512) ? *(const bf16x8*)(Ichar + arow * 512 + k1)
                    : *(const bf16x8*)(embb + (arow * NS_ + s) * 256 + (k1 - 512));
#pragma unroll
    for (int ni = 0; ni < 4; ++ni) {
      const long wrow = g * 512 + j0 + ni * 16 + l15;
      b0r[ni] = *(const bf16x8*)(WihE + wrow * 768 + k0);
      b1r[ni] = *(const bf16x8*)(WihE + wrow * 768 + k1);
    }
#pragma unroll
    for (int ni = 0; ni < 4; ++ni) {
      acc[ni] = __builtin_amdgcn_mfma_f32_16x16x32_bf16(a0, b0r[ni], acc[ni], 0, 0, 0);
      acc[ni] = __builtin_amdgcn_mfma_f32_16x16x32_bf16(a1, b1r[ni], acc[ni], 0, 0, 0);
    }
  }
#pragma unroll
  for (int ni = 0; ni < 4; ++ni)
#pragma unroll
    for (int r = 0; r < 4; ++r) {
      const int rl = mi * 16 + lq * 4 + r;
      const int cl = ni * 16 + l15;
      gs[(g * 32 + rl) * 65 + cl] = acc[ni][r];
    }
  __syncthreads();
#pragma unroll
  for (int i = 0; i < 4; ++i) {
    const int e = tid + i * 512;
    const int r = e >> 6, c = e & 63;
    const long b = b0 + r;
    const int j = j0 + c;
    const float* ggh = hpgh + b * 2560 + 512;
    const float ig = sigm_f(gs[(0 * 32 + r) * 65 + c] + ggh[j]);
    const float fg = sigm_f(gs[(1 * 32 + r) * 65 + c] + ggh[512 + j]);
    const float gg = tanh_f(gs[(2 * 32 + r) * 65 + c] + ggh[1024 + j]);
    const float og = sigm_f(gs[(3 * 32 + r) * 65 + c] + ggh[1536 + j]);
    const float cn = fg * cbuf[b * 512 + j] + ig * gg;
    cbuf[b * 512 + j] = cn;
    const float h = og * tanh_f(cn);
    hid_out[(b * NS_ + s) * 512 + j] = h;
    hwr[b * 512 + j] = f2bf(h);
  }
}

__global__ __launch_bounds__(256) void probs_k(
    const float* __restrict__ Af, const unsigned short* __restrict__ Wg,
    const float* __restrict__ bias, float* __restrict__ outp) {
  const int tid = threadIdx.x, w = tid >> 6, l = tid & 63, l15 = l & 15, lq = l >> 4;
  const long mrow = (long)blockIdx.y * 64 + w * 16 + l15;
  const int nbase = blockIdx.x * 64;
  f32x4 acc[4] = {};
  for (int kt = 0; kt < 512; kt += 32) {
    const int k = kt + lq * 8;
    const float4 av0 = *(const float4*)(Af + mrow * 512 + k);
    const float4 av1 = *(const float4*)(Af + mrow * 512 + k + 4);
    bf16x8 a;
    a[0] = (short)f2bf(av0.x); a[1] = (short)f2bf(av0.y);
    a[2] = (short)f2bf(av0.z); a[3] = (short)f2bf(av0.w);
    a[4] = (short)f2bf(av1.x); a[5] = (short)f2bf(av1.y);
    a[6] = (short)f2bf(av1.z); a[7] = (short)f2bf(av1.w);
#pragma unroll
    for (int nb = 0; nb < 4; ++nb) {
      const bf16x8 b = *(const bf16x8*)(Wg + (long)(nbase + nb * 16 + l15) * 512 + k);
      acc[nb] = __builtin_amdgcn_mfma_f32_16x16x32_bf16(a, b, acc[nb], 0, 0, 0);
    }
  }
#pragma unroll
  for (int nb = 0; nb < 4; ++nb) {
    const int colg = nbase + nb * 16 + l15;
    if (colg >= NCLS_) continue;
    const float bv = bias[colg];
#pragma unroll
    for (int r = 0; r < 4; ++r) {
      const long rowg = (long)blockIdx.y * 64 + w * 16 + lq * 4 + r;
      outp[rowg * NCLS_ + colg] = acc[nb][r] + bv;
    }
  }
}

// ============ prologue helpers ============
__global__ void cvt_f32_bf16_k(const float* __restrict__ in, unsigned short* __restrict__ out, long n) {
  const long i = ((long)blockIdx.x * 256 + threadIdx.x) * 4;
  if (i + 4 <= n) {
    const float4 v = *(const float4*)(in + i);
    ushort4 o;
    o.x = f2bf(v.x); o.y = f2bf(v.y); o.z = f2bf(v.z); o.w = f2bf(v.w);
    *(ushort4*)(out + i) = o;
  }
}

__global__ void embed_k(const float* __restrict__ emb_table, const int* __restrict__ text,
                        unsigned short* __restrict__ out) {
  const int bs = blockIdx.x, j = threadIdx.x;
  const int t = text[bs];
  out[(long)bs * 256 + j] = f2bf(emb_table[(long)t * 256 + j]);
}

__global__ void pack_WA_k(const float* __restrict__ W_h2h, const float* __restrict__ W_hh,
                          unsigned short* __restrict__ out) {
  const long idx = (long)blockIdx.x * 256 + threadIdx.x;
  const int row = (int)(idx >> 9), k = (int)(idx & 511);
  const float v = (row < 512) ? W_h2h[(long)row * 512 + k] : W_hh[(long)(row - 512) * 512 + k];
  out[idx] = f2bf(v);
}

__global__ void pack_wfz_k(const float* __restrict__ Wf, const float* __restrict__ Wz, int zoff,
                           unsigned short* __restrict__ out) {
  const long idx = (long)blockIdx.x * 256 + threadIdx.x;
  const int row = (int)(idx >> 9), k = (int)(idx & 511);
  const float v = (row < 512) ? Wf[(long)row * 512 + k]
                              : Wz[(long)(row - 512) * 1024 + zoff + k];
  out[idx] = f2bf(v);
}

__global__ void pack_Wgen_k(const float* __restrict__ W_gen, unsigned short* __restrict__ out) {
  const long idx = (long)blockIdx.x * 256 + threadIdx.x;  // 128*512
  const int row = (int)(idx >> 9), k = (int)(idx & 511);
  out[idx] = (row < NCLS_) ? f2bf(W_gen[(long)row * 512 + k]) : (unsigned short)0;
}

__global__ void pack_bias_k(const float* __restrict__ b_h2h, const float* __restrict__ b_ih,
                            const float* __restrict__ b_hh, const float* __restrict__ bf2,
                            const float* __restrict__ bz,
                            float* __restrict__ biasA, float* __restrict__ biasFZ) {
  const int i = blockIdx.x * 256 + threadIdx.x;  // 3584
  if (i < 2560) {
    biasA[i] = (i < 512) ? b_h2h[i] : (b_ih[i - 512] + b_hh[i - 512]);
  } else {
    const int j = i - 2560;
    biasFZ[j] = (j < 512) ? bf2[j] : bz[j - 512];
  }
}

extern "C" void kernel_launch(void* const* d_in, const int* in_sizes, int n_in,
                              void* d_out, int out_size, void* d_ws, size_t ws_size,
                              hipStream_t stream) {
  (void)in_sizes; (void)n_in; (void)out_size; (void)ws_size;
  const float* batch_H  = (const float*)d_in[0];
  const float* AS       = (const float*)d_in[1];
  const int*   text     = (const int*)d_in[2];
  const float* W_i2h    = (const float*)d_in[3];
  const float* W_h2h    = (const float*)d_in[4];
  const float* b_h2h    = (const float*)d_in[5];
  const float* w_score  = (const float*)d_in[6];
  const float* W_ih     = (const float*)d_in[7];
  const float* W_hh     = (const float*)d_in[8];
  const float* b_ih     = (const float*)d_in[9];
  const float* b_hh     = (const float*)d_in[10];
  const float* Wf1      = (const float*)d_in[11];
  const float* bf1      = (const float*)d_in[12];
  const float* Wf2      = (const float*)d_in[13];
  const float* bf2      = (const float*)d_in[14];
  const float* Wz       = (const float*)d_in[15];
  const float* bz       = (const float*)d_in[16];
  const float* W_gen    = (const float*)d_in[17];
  const float* b_gen    = (const float*)d_in[18];
  const float* emb_tab  = (const float*)d_in[19];

  float* out = (float*)d_out;
  float* out_probs = out;                       // [B,NS,NCLS]
  float* out_attn  = out + 1291264;             // [B,T,NS]
  float* out_hid   = out + 2143232;             // [B,NS,H]
  float* out_char  = out + 8958976;             // [B,NS,H]

  char* wsp = (char*)d_ws;
  auto alloc = [&](size_t bytes) { char* p = wsp; wsp += (bytes + 255) & ~(size_t)255; return p; };
  unsigned short* bH    = (unsigned short*)alloc(33554432);  // [B,T,C] bf16
  unsigned short* Hproj = (unsigned short*)alloc(33554432);  // [B,T,H] bf16
  unsigned short* ASb   = (unsigned short*)alloc(13631488);  // [B*NS,512] bf16 (prologue only)
  unsigned short* embb  = (unsigned short*)alloc(6815744);   // [B,NS,NEMB] bf16
  unsigned short* FZpre = (unsigned short*)alloc(27262976);  // [B*NS,1024] bf16
  unsigned short* WA    = (unsigned short*)alloc(2621440);   // [2560,512]
  unsigned short* Wfz   = (unsigned short*)alloc(1048576);   // [1024,512]  (Wf1 | Wz-left)
  unsigned short* Wfz2  = (unsigned short*)alloc(1048576);   // [1024,512]  (Wf2 | Wz-right)
  unsigned short* WihE  = (unsigned short*)alloc(3145728);   // [2048,768]
  unsigned short* Wgenb = (unsigned short*)alloc(131072);    // [128,512]
  unsigned short* Wi2hb = (unsigned short*)alloc(524288);    // [512,512]
  float* biasA          = (float*)alloc(10240);              // [2560]
  float* biasFZ         = (float*)alloc(4096);               // [1024]
  // ---- aliased into ASb (dead after FZpre GEMM) ----
  char* ab = (char*)ASb;
  float* hpgh           = (float*)(ab);                      // [512,2560] f32 (5242880)
  unsigned short* ctx   = (unsigned short*)(ab + 5242880);   // [B,512] bf16 (524288)
  unsigned short* Ichar = (unsigned short*)(ab + 5767168);   // [B,512] bf16 (524288)
  float* cbuf           = (float*)(ab + 6291456);            // [B,512] f32 (1048576)
  unsigned short* hbuf  = (unsigned short*)(ab + 7340032);   // 2x [B,512] bf16 (1048576)

  // -------- prologue --------
  cvt_f32_bf16_k<<<dim3(16384), dim3(256), 0, stream>>>(batch_H, bH, 16777216);
  cvt_f32_bf16_k<<<dim3(6656), dim3(256), 0, stream>>>(AS, ASb, 6815744);
  cvt_f32_bf16_k<<<dim3(256), dim3(256), 0, stream>>>(W_i2h, Wi2hb, 262144);
  cvt_f32_bf16_k<<<dim3(1536), dim3(256), 0, stream>>>(W_ih, WihE, 1572864);
  embed_k<<<dim3(13312), dim3(256), 0, stream>>>(emb_tab, text, embb);
  pack_WA_k<<<dim3(5120), dim3(256), 0, stream>>>(W_h2h, W_hh, WA);
  pack_wfz_k<<<dim3(2048), dim3(256), 0, stream>>>(Wf1, Wz, 0, Wfz);
  pack_wfz_k<<<dim3(2048), dim3(256), 0, stream>>>(Wf2, Wz, 512, Wfz2);
  pack_Wgen_k<<<dim3(256), dim3(256), 0, stream>>>(W_gen, Wgenb);
  pack_bias_k<<<dim3(14), dim3(256), 0, stream>>>(b_h2h, b_ih, b_hh, bf2, bz, biasA, biasFZ);

  // H_proj = batch_H @ W_i2h^T  (M=32768, N=512, K=512) -> bf16
  gemm_tiled_k<false><<<dim3(4, 256), dim3(256), 0, stream>>>(
      bH, Wi2hb, nullptr, nullptr, Hproj, 512, 512, 512);

  // FZpre = AS @ [Wf2 | Wz-right]^T + [bf2 | bz]  (M=13312, N=1024, K=512) -> bf16
  gemm_tiled_k<false><<<dim3(8, 104), dim3(256), 0, stream>>>(
      ASb, Wfz2, biasFZ, nullptr, FZpre, 512, 1024, 1024);

  // ASb region dead -> init aliased state buffers
  hipMemsetAsync(cbuf, 0, 1048576, stream);
  hipMemsetAsync(hbuf, 0, 1048576, stream);

  // -------- cooperative 26-step scan + probs (grid = 256 blocks) --------
  CoopArgs ca;
  ca.Hproj = Hproj; ca.bH = bH; ca.WA = WA; ca.Wfz = Wfz; ca.FZpre = FZpre;
  ca.WihE = WihE; ca.embb = embb; ca.Wgenb = Wgenb;
  ca.biasA = biasA; ca.w_score = w_score; ca.bf1 = bf1; ca.b_gen = b_gen;
  ca.hpgh = hpgh; ca.out_attn = out_attn; ca.out_char = out_char;
  ca.out_hid = out_hid; ca.out_probs = out_probs; ca.cbuf = cbuf;
  ca.ctx = ctx; ca.Ichar = Ichar; ca.hbuf = hbuf;
  void* kargs[] = { (void*)&ca };
  hipError_t cerr = hipLaunchCooperativeKernel((const void*)scan_coop_k, dim3(256), dim3(256),
                                               kargs, 0, stream);
  if (cerr != hipSuccess) {
    // -------- fallback: proven multi-kernel path --------
    for (int s = 0; s < NS_; ++s) {
      unsigned short* hrd = hbuf + (s & 1) * 262144;
      unsigned short* hwr = hbuf + ((s + 1) & 1) * 262144;
      gemm_hpgh_k<<<dim3(40, 8), dim3(256), 0, stream>>>(hrd, WA, biasA, hpgh);
      attn_step_k<<<dim3(512), dim3(512), 0, stream>>>(Hproj, bH, hpgh, w_score, out_attn, ctx, s);
      gated_fused_k<<<dim3(8, 8), dim3(512), 0, stream>>>(
          ctx, Wfz, FZpre, bf1, Ichar, out_char, s);
      gates_lstm_k<<<dim3(8, 16), dim3(512), 0, stream>>>(
          Ichar, embb, WihE, hpgh, cbuf, out_hid, hwr, s);
    }
    probs_k<<<dim3(2, 208), dim3(256), 0, stream>>>(out_hid, Wgenb, b_gen, out_probs);
  }
}

// Round 6
// 5110.778 us; speedup vs baseline: 1.0597x; 1.0597x over previous
//
#include <hip/hip_runtime.h>
#include <hip/hip_cooperative_groups.h>

namespace cg = cooperative_groups;

#define NS_ 26
#define NCLS_ 97

typedef short bf16x8 __attribute__((ext_vector_type(8)));
typedef float f32x4 __attribute__((ext_vector_type(4)));

__device__ __forceinline__ unsigned short f2bf(float f) {
  union { float f; unsigned u; } v; v.f = f;
  unsigned r = v.u + 0x7fffu + ((v.u >> 16) & 1u);
  return (unsigned short)(r >> 16);
}
__device__ __forceinline__ float bf2f(unsigned short h) {
  union { unsigned u; float f; } v; v.u = ((unsigned)h) << 16;
  return v.f;
}
__device__ __forceinline__ float sigm_f(float x) { return 1.f / (1.f + __expf(-x)); }
__device__ __forceinline__ float tanh_f(float x) { return 1.f - 2.f / (1.f + __expf(2.f * x)); }

__device__ __forceinline__ void gl_lds16(const void* g, void* l) {
  __builtin_amdgcn_global_load_lds(
      (const __attribute__((address_space(1))) unsigned int*)g,
      (__attribute__((address_space(3))) unsigned int*)l, 16, 0, 0);
}

// ============ tiled 128x128 GEMM (prologue) ============
template <bool OUTF>
__global__ __launch_bounds__(256) void gemm_tiled_k(
    const unsigned short* __restrict__ Ag, const unsigned short* __restrict__ Bg,
    const float* __restrict__ bias, float* __restrict__ outF,
    unsigned short* __restrict__ outB, int K, long ldo, int Nvalid) {
  __shared__ unsigned short As[128 * 64];
  __shared__ unsigned short Bs[128 * 64];
  const int tid = threadIdx.x;
  const int w = tid >> 6, l = tid & 63;
  const int l15 = l & 15, lq = l >> 4;
  const int wm = w >> 1, wn = w & 1;
  const long rowBase = (long)blockIdx.y * 128;
  const long colBase = (long)blockIdx.x * 128;
  const int lrow = l >> 3, ps_st = l & 7;
  f32x4 acc[4][4] = {};
  for (int kt = 0; kt < K; kt += 64) {
#pragma unroll
    for (int i = 0; i < 4; ++i) {
      const int row = i * 32 + w * 8 + lrow;
      const int ls = ps_st ^ (row & 7);
      gl_lds16(Ag + (rowBase + row) * K + kt + ls * 8, As + i * 2048 + w * 512);
      gl_lds16(Bg + (colBase + row) * K + kt + ls * 8, Bs + i * 2048 + w * 512);
    }
    __syncthreads();
#pragma unroll
    for (int kh = 0; kh < 2; ++kh) {
      bf16x8 af[4], bfr[4];
#pragma unroll
      for (int mi = 0; mi < 4; ++mi) {
        const int row = wm * 64 + mi * 16 + l15;
        const int ps = (kh * 4 + lq) ^ (row & 7);
        af[mi] = *(const bf16x8*)(As + row * 64 + ps * 8);
      }
#pragma unroll
      for (int ni = 0; ni < 4; ++ni) {
        const int row = wn * 64 + ni * 16 + l15;
        const int ps = (kh * 4 + lq) ^ (row & 7);
        bfr[ni] = *(const bf16x8*)(Bs + row * 64 + ps * 8);
      }
#pragma unroll
      for (int mi = 0; mi < 4; ++mi)
#pragma unroll
        for (int ni = 0; ni < 4; ++ni)
          acc[mi][ni] = __builtin_amdgcn_mfma_f32_16x16x32_bf16(af[mi], bfr[ni], acc[mi][ni], 0, 0, 0);
    }
    __syncthreads();
  }
#pragma unroll
  for (int mi = 0; mi < 4; ++mi)
#pragma unroll
    for (int ni = 0; ni < 4; ++ni) {
      const long gcol = colBase + wn * 64 + ni * 16 + l15;
      if (gcol >= Nvalid) continue;
      const float bv = bias ? bias[gcol] : 0.f;
#pragma unroll
      for (int r = 0; r < 4; ++r) {
        const long grow = rowBase + wm * 64 + mi * 16 + lq * 4 + r;
        const float v = acc[mi][ni][r] + bv;
        if (OUTF) outF[grow * ldo + gcol] = v;
        else      outB[grow * ldo + gcol] = f2bf(v);
      }
    }
}

// ============ persistent cooperative scan kernel (256 blocks x 1024 thr) ============
struct CoopArgs {
  const unsigned short* Hproj;   // [B,64,512] bf16
  const unsigned short* bH;      // [B,64,512] bf16
  const unsigned short* WA;      // [2560,512] bf16
  const unsigned short* Wfz;     // [1024,512] bf16 (Wf1 | Wz-left)
  const unsigned short* FZpre;   // [B*NS,1024] bf16
  const unsigned short* WihE;    // [2048,768] bf16
  const unsigned short* embb;    // [B,NS,256] bf16
  const unsigned short* Wgenb;   // [128,512] bf16
  const float* biasA;            // [2560]
  const float* w_score;          // [512]
  const float* bf1;              // [512]
  const float* b_gen;            // [97]
  float* hpgh;                   // [512,2560]
  float* out_attn;               // [B,64,NS]
  float* out_char;               // [B,NS,512]
  float* out_hid;                // [B,NS,512]
  float* out_probs;              // [B*NS,97]
  float* cbuf;                   // [B,512]
  unsigned short* ctx;           // [B,512] bf16
  unsigned short* Ichar;         // [B,512] bf16
  unsigned short* hbuf;          // 2x [B,512] bf16
};

__global__ __launch_bounds__(1024, 4) void scan_coop_k(CoopArgs A) {
  cg::grid_group grid = cg::this_grid();
  __shared__ float smem[4864];   // [0..4352): phase scratch; [4352..4864): ws_t
  float* ws_t = smem + 4352;
  const int tid = threadIdx.x;
  const int sb = tid >> 8;           // sub-block 0..3 (256 thr)
  const int stid = tid & 255;
  const int sw = stid >> 6;          // wave within sub-block 0..3
  const int l = tid & 63, l15 = l & 15, lq = l >> 4;
  const int bx = blockIdx.x;

  if (tid < 512) ws_t[((tid & 7) << 6) + (tid >> 3)] = A.w_score[tid];
  __syncthreads();

  for (int s = 0; s < NS_; ++s) {
    const unsigned short* hrd = A.hbuf + (s & 1) * 262144;
    unsigned short* hwr = A.hbuf + ((s + 1) & 1) * 262144;

    // ---- P1: hpgh = h @ [W_h2h|W_hh]^T + biasA  (320 units of 64x64, 1 unit/sub-block) ----
    {
      const int u = sb * 256 + bx;
      if (u < 320) {
        const int jt = u % 40, bt = u / 40;
        const int nbase = jt * 64;
        const long mrow = (long)bt * 64 + sw * 16 + l15;
        f32x4 acc[4] = {};
        for (int kt = 0; kt < 512; kt += 64) {
          const int k0 = kt + lq * 8, k1 = k0 + 32;
          const bf16x8 a0 = *(const bf16x8*)(hrd + mrow * 512 + k0);
          const bf16x8 a1 = *(const bf16x8*)(hrd + mrow * 512 + k1);
          bf16x8 b0[4], b1[4];
#pragma unroll
          for (int ni = 0; ni < 4; ++ni) {
            const long wr = nbase + ni * 16 + l15;
            b0[ni] = *(const bf16x8*)(A.WA + wr * 512 + k0);
            b1[ni] = *(const bf16x8*)(A.WA + wr * 512 + k1);
          }
#pragma unroll
          for (int ni = 0; ni < 4; ++ni) {
            acc[ni] = __builtin_amdgcn_mfma_f32_16x16x32_bf16(a0, b0[ni], acc[ni], 0, 0, 0);
            acc[ni] = __builtin_amdgcn_mfma_f32_16x16x32_bf16(a1, b1[ni], acc[ni], 0, 0, 0);
          }
        }
#pragma unroll
        for (int ni = 0; ni < 4; ++ni) {
          const int colg = nbase + ni * 16 + l15;
          const float bv = A.biasA[colg];
#pragma unroll
          for (int r = 0; r < 4; ++r) {
            const long rowg = (long)bt * 64 + sw * 16 + lq * 4 + r;
            A.hpgh[rowg * 2560 + colg] = acc[ni][r] + bv;
          }
        }
      }
    }
    grid.sync();

    // ---- P2: attention — 2 rows/block, 512 thr (8 waves) per row ----
    {
      const int ssb = tid >> 9;          // row-team 0/1
      const int sstid = tid & 511;
      const int b = bx * 2 + ssb;
      float* S = smem + ssb * 1088;      // hp_t[512] | e[64] | csum[512]
      // load hp transposed: S[(h&7)*64 + (h>>3)] = hp[h]
      S[((sstid & 7) << 6) + (sstid >> 3)] = A.hpgh[(long)b * 2560 + sstid];
      __syncthreads();
      // score: wave w8 handles t = w8*8 .. +8; lane l covers h = l*8..+8 via transposed LDS
      const int w8 = sstid >> 6;
      float* e_s = S + 512;
#pragma unroll
      for (int tt = 0; tt < 8; ++tt) {
        const int t = w8 * 8 + tt;
        const bf16x8 hv = *(const bf16x8*)(A.Hproj + ((long)b * 64 + t) * 512 + l * 8);
        float acc = 0.f;
#pragma unroll
        for (int j = 0; j < 8; ++j)
          acc += tanh_f(bf2f((unsigned short)hv[j]) + S[j * 64 + l]) * ws_t[j * 64 + l];
        acc += __shfl_xor(acc, 1);
        acc += __shfl_xor(acc, 2);
        acc += __shfl_xor(acc, 4);
        acc += __shfl_xor(acc, 8);
        acc += __shfl_xor(acc, 16);
        acc += __shfl_xor(acc, 32);
        if (l == 0) e_s[t] = acc;
      }
      __syncthreads();
      if (sstid < 64) {
        const float e = e_s[sstid];
        float m = e;
        for (int off = 32; off; off >>= 1) m = fmaxf(m, __shfl_xor(m, off));
        const float p = __expf(e - m);
        float sum = p;
        for (int off = 32; off; off >>= 1) sum += __shfl_xor(sum, off);
        const float al = p / sum;
        e_s[sstid] = al;
        A.out_attn[((long)b * 64 + sstid) * NS_ + s] = al;
      }
      __syncthreads();
      // context: 2 t-halves x 256 col-pair threads
      const int half = sstid >> 8, jj = sstid & 255;
      float c0 = 0.f, c1 = 0.f;
      const unsigned* bhp = (const unsigned*)(A.bH + ((long)b * 64 + half * 32) * 512) + jj;
#pragma unroll 8
      for (int t = 0; t < 32; ++t) {
        const float al = e_s[half * 32 + t];
        const unsigned pv = bhp[(long)t * 256];
        c0 += al * bf2f((unsigned short)(pv & 0xffffu));
        c1 += al * bf2f((unsigned short)(pv >> 16));
      }
      float* csum = S + 576;
      if (half) { csum[jj * 2] = c0; csum[jj * 2 + 1] = c1; }
      __syncthreads();
      if (!half) {
        c0 += csum[jj * 2];
        c1 += csum[jj * 2 + 1];
        ((unsigned*)A.ctx)[(long)b * 256 + jj] = (unsigned)f2bf(c0) | ((unsigned)f2bf(c1) << 16);
      }
      __syncthreads();
    }
    grid.sync();

    // ---- P3: gated fusion (512 units of 16r x 32c, 1 unit/sub-block, sb<2) ----
    {
      const int u = sb * 256 + bx;
      const bool act = u < 512;
      int j0 = 0, b0 = 0;
      f32x4 acc = {};
      const int which = sw >> 1, nh = sw & 1;
      if (act) {
        j0 = (u & 15) * 32; b0 = (u >> 4) * 16;
        const long arow = b0 + l15;
        const long gw = (long)(which ? 512 : 0) + j0 + nh * 16 + l15;
        for (int kt = 0; kt < 512; kt += 64) {
          const int k0 = kt + lq * 8, k1 = k0 + 32;
          const bf16x8 a0 = *(const bf16x8*)(A.ctx + arow * 512 + k0);
          const bf16x8 a1 = *(const bf16x8*)(A.ctx + arow * 512 + k1);
          const bf16x8 w0 = *(const bf16x8*)(A.Wfz + gw * 512 + k0);
          const bf16x8 w1 = *(const bf16x8*)(A.Wfz + gw * 512 + k1);
          acc = __builtin_amdgcn_mfma_f32_16x16x32_bf16(a0, w0, acc, 0, 0, 0);
          acc = __builtin_amdgcn_mfma_f32_16x16x32_bf16(a1, w1, acc, 0, 0, 0);
        }
        float* S = smem + sb * 1088;
#pragma unroll
        for (int r = 0; r < 4; ++r)
          S[which * 528 + (lq * 4 + r) * 33 + nh * 16 + l15] = acc[r];
      }
      __syncthreads();
      if (act) {
        const float* S = smem + sb * 1088;
#pragma unroll
        for (int i = 0; i < 2; ++i) {
          const int e = stid + i * 256;
          const int r = e >> 5, c = e & 31;
          const long b = b0 + r;
          const int j = j0 + c;
          const float f1 = tanh_f(S[r * 33 + c] + A.bf1[j]);
          const float zc = S[528 + r * 33 + c];
          const long pr = (b * NS_ + s) * 1024;
          const float f2 = tanh_f(bf2f(A.FZpre[pr + j]));
          const float z = sigm_f(zc + bf2f(A.FZpre[pr + 512 + j]));
          const float I = z * f1 + (1.f - z) * f2;
          A.out_char[(b * NS_ + s) * 512 + j] = I;
          A.Ichar[b * 512 + j] = f2bf(I);
        }
      }
      __syncthreads();
    }
    grid.sync();

    // ---- P4: gates GEMM + LSTM (1024 units of 16r x 16c, wave = gate) ----
    {
      const int u = sb * 256 + bx;
      const int j0 = (u & 31) * 16, b0 = (u >> 5) * 16;
      const int g = sw;
      f32x4 acc = {};
      const long arow = b0 + l15;
      const long wrow = (long)g * 512 + j0 + l15;
      for (int kt = 0; kt < 768; kt += 64) {
        const int k0 = kt + lq * 8, k1 = k0 + 32;
        const bf16x8 a0 = (k0 < 512)
            ? *(const bf16x8*)(A.Ichar + arow * 512 + k0)
            : *(const bf16x8*)(A.embb + (arow * NS_ + s) * 256 + (k0 - 512));
        const bf16x8 a1 = (k1 < 512)
            ? *(const bf16x8*)(A.Ichar + arow * 512 + k1)
            : *(const bf16x8*)(A.embb + (arow * NS_ + s) * 256 + (k1 - 512));
        const bf16x8 w0 = *(const bf16x8*)(A.WihE + wrow * 768 + k0);
        const bf16x8 w1 = *(const bf16x8*)(A.WihE + wrow * 768 + k1);
        acc = __builtin_amdgcn_mfma_f32_16x16x32_bf16(a0, w0, acc, 0, 0, 0);
        acc = __builtin_amdgcn_mfma_f32_16x16x32_bf16(a1, w1, acc, 0, 0, 0);
      }
      float* S = smem + sb * 1088;
#pragma unroll
      for (int r = 0; r < 4; ++r)
        S[g * 272 + (lq * 4 + r) * 17 + l15] = acc[r];
      __syncthreads();
      {
        const float* S2 = smem + sb * 1088;
        const int r = stid >> 4, c = stid & 15;
        const long b = b0 + r;
        const int j = j0 + c;
        const float* ggh = A.hpgh + b * 2560 + 512;
        const float ig = sigm_f(S2[r * 17 + c] + ggh[j]);
        const float fg = sigm_f(S2[272 + r * 17 + c] + ggh[512 + j]);
        const float gg = tanh_f(S2[544 + r * 17 + c] + ggh[1024 + j]);
        const float og = sigm_f(S2[816 + r * 17 + c] + ggh[1536 + j]);
        const float cn = fg * A.cbuf[b * 512 + j] + ig * gg;
        A.cbuf[b * 512 + j] = cn;
        const float h = og * tanh_f(cn);
        A.out_hid[(b * NS_ + s) * 512 + j] = h;
        hwr[b * 512 + j] = f2bf(h);
      }
      __syncthreads();
    }
    grid.sync();
  }

  // ---- P5: probs = out_hid @ W_gen^T + b_gen (416 units of 64x64) ----
  {
    const int u = sb * 256 + bx;
    if (u < 416) {
      const int jt = u & 1, bt = u >> 1;
      const int nbase = jt * 64;
      const long mrow = (long)bt * 64 + sw * 16 + l15;
      f32x4 acc[4] = {};
      for (int kt = 0; kt < 512; kt += 32) {
        const int k = kt + lq * 8;
        const float4 av0 = *(const float4*)(A.out_hid + mrow * 512 + k);
        const float4 av1 = *(const float4*)(A.out_hid + mrow * 512 + k + 4);
        bf16x8 a;
        a[0] = (short)f2bf(av0.x); a[1] = (short)f2bf(av0.y);
        a[2] = (short)f2bf(av0.z); a[3] = (short)f2bf(av0.w);
        a[4] = (short)f2bf(av1.x); a[5] = (short)f2bf(av1.y);
        a[6] = (short)f2bf(av1.z); a[7] = (short)f2bf(av1.w);
#pragma unroll
        for (int nb = 0; nb < 4; ++nb) {
          const bf16x8 b = *(const bf16x8*)(A.Wgenb + (long)(nbase + nb * 16 + l15) * 512 + k);
          acc[nb] = __builtin_amdgcn_mfma_f32_16x16x32_bf16(a, b, acc[nb], 0, 0, 0);
        }
      }
#pragma unroll
      for (int nb = 0; nb < 4; ++nb) {
        const int colg = nbase + nb * 16 + l15;
        if (colg >= NCLS_) continue;
        const float bv = A.b_gen[colg];
#pragma unroll
        for (int r = 0; r < 4; ++r) {
          const long rowg = (long)bt * 64 + sw * 16 + lq * 4 + r;
          A.out_probs[rowg * NCLS_ + colg] = acc[nb][r] + bv;
        }
      }
    }
  }
}

// ============ fallback per-step kernels (proven round-3 path) ============
__global__ __launch_bounds__(256) void gemm_hpgh_k(
    const unsigned short* __restrict__ h, const unsigned short* __restrict__ WA,
    const float* __restrict__ biasA, float* __restrict__ hpgh) {
  const int tid = threadIdx.x, w = tid >> 6, l = tid & 63, l15 = l & 15, lq = l >> 4;
  const long mrow = (long)blockIdx.y * 64 + w * 16 + l15;
  const int nbase = blockIdx.x * 64;
  f32x4 acc[4] = {};
  for (int kt = 0; kt < 512; kt += 64) {
    const int k0 = kt + lq * 8, k1 = k0 + 32;
    const bf16x8 a0 = *(const bf16x8*)(h + mrow * 512 + k0);
    const bf16x8 a1 = *(const bf16x8*)(h + mrow * 512 + k1);
    bf16x8 b0[4], b1[4];
#pragma unroll
    for (int nb = 0; nb < 4; ++nb) {
      const long wr = nbase + nb * 16 + l15;
      b0[nb] = *(const bf16x8*)(WA + wr * 512 + k0);
      b1[nb] = *(const bf16x8*)(WA + wr * 512 + k1);
    }
#pragma unroll
    for (int nb = 0; nb < 4; ++nb) {
      acc[nb] = __builtin_amdgcn_mfma_f32_16x16x32_bf16(a0, b0[nb], acc[nb], 0, 0, 0);
      acc[nb] = __builtin_amdgcn_mfma_f32_16x16x32_bf16(a1, b1[nb], acc[nb], 0, 0, 0);
    }
  }
#pragma unroll
  for (int nb = 0; nb < 4; ++nb) {
    const int colg = nbase + nb * 16 + l15;
    const float bv = biasA[colg];
#pragma unroll
    for (int r = 0; r < 4; ++r) {
      const long rowg = (long)blockIdx.y * 64 + w * 16 + lq * 4 + r;
      hpgh[rowg * 2560 + colg] = acc[nb][r] + bv;
    }
  }
}

__global__ __launch_bounds__(512) void attn_step_k(
    const unsigned short* __restrict__ Hproj, const unsigned short* __restrict__ bH,
    const float* __restrict__ hpgh, const float* __restrict__ w_score,
    float* __restrict__ attn_map, unsigned short* __restrict__ ctx, int s) {
  const int b = blockIdx.x, tid = threadIdx.x;
  __shared__ float hp_s[512], ws_s[512], e_s[64], csum[512];
  hp_s[tid] = hpgh[(long)b * 2560 + tid];
  ws_s[tid] = w_score[tid];
  __syncthreads();
  const int w = tid >> 6, l = tid & 63;
  const unsigned short* Hrow = Hproj + ((long)b * 64 + w * 8) * 512 + l * 8;
#pragma unroll
  for (int tt = 0; tt < 8; ++tt) {
    const bf16x8 hv = *(const bf16x8*)(Hrow + tt * 512);
    float acc = 0.f;
#pragma unroll
    for (int j = 0; j < 8; ++j) {
      const int h = l * 8 + j;
      acc += tanh_f(bf2f((unsigned short)hv[j]) + hp_s[h]) * ws_s[h];
    }
    acc += __shfl_xor(acc, 1);
    acc += __shfl_xor(acc, 2);
    acc += __shfl_xor(acc, 4);
    acc += __shfl_xor(acc, 8);
    acc += __shfl_xor(acc, 16);
    acc += __shfl_xor(acc, 32);
    if (l == 0) e_s[w * 8 + tt] = acc;
  }
  __syncthreads();
  if (tid < 64) {
    const float e = e_s[tid];
    float m = e;
    for (int off = 32; off; off >>= 1) m = fmaxf(m, __shfl_xor(m, off));
    const float p = __expf(e - m);
    float sum = p;
    for (int off = 32; off; off >>= 1) sum += __shfl_xor(sum, off);
    const float a = p / sum;
    e_s[tid] = a;
    attn_map[((long)b * 64 + tid) * NS_ + s] = a;
  }
  __syncthreads();
  const int half = tid >> 8, jj = tid & 255;
  float c0 = 0.f, c1 = 0.f;
  const unsigned* bhp = (const unsigned*)(bH + ((long)b * 64 + half * 32) * 512) + jj;
#pragma unroll 8
  for (int t = 0; t < 32; ++t) {
    const float a = e_s[half * 32 + t];
    const unsigned pv = bhp[(long)t * 256];
    c0 += a * bf2f((unsigned short)(pv & 0xffffu));
    c1 += a * bf2f((unsigned short)(pv >> 16));
  }
  if (half) { csum[jj * 2] = c0; csum[jj * 2 + 1] = c1; }
  __syncthreads();
  if (!half) {
    c0 += csum[jj * 2];
    c1 += csum[jj * 2 + 1];
    ((unsigned*)ctx)[(long)b * 256 + jj] = (unsigned)f2bf(c0) | ((unsigned)f2bf(c1) << 16);
  }
}

__global__ __launch_bounds__(512) void gated_fused_k(
    const unsigned short* __restrict__ ctx, const unsigned short* __restrict__ Wfz,
    const unsigned short* __restrict__ FZpre, const float* __restrict__ bf1,
    unsigned short* __restrict__ Ichar, float* __restrict__ Char_out, int s) {
  __shared__ float ls[2 * 64 * 65];
  const int tid = threadIdx.x, w = tid >> 6, l = tid & 63, l15 = l & 15, lq = l >> 4;
  const int b0 = blockIdx.y * 64, j0 = blockIdx.x * 64;
  const int mi2 = w & 1, nq = w >> 1;
  f32x4 acc[2][2] = {};
  for (int kt = 0; kt < 512; kt += 64) {
    const int k0 = kt + lq * 8, k1 = k0 + 32;
    bf16x8 a0[2], a1[2], bb0[2], bb1[2];
#pragma unroll
    for (int mi = 0; mi < 2; ++mi) {
      const long row = b0 + mi2 * 32 + mi * 16 + l15;
      a0[mi] = *(const bf16x8*)(ctx + row * 512 + k0);
      a1[mi] = *(const bf16x8*)(ctx + row * 512 + k1);
    }
#pragma unroll
    for (int ni = 0; ni < 2; ++ni) {
      const int wl = nq * 32 + ni * 16 + l15;
      const long gw = (wl < 64) ? (j0 + wl) : (512 + j0 + wl - 64);
      bb0[ni] = *(const bf16x8*)(Wfz + gw * 512 + k0);
      bb1[ni] = *(const bf16x8*)(Wfz + gw * 512 + k1);
    }
#pragma unroll
    for (int mi = 0; mi < 2; ++mi)
#pragma unroll
      for (int ni = 0; ni < 2; ++ni) {
        acc[mi][ni] = __builtin_amdgcn_mfma_f32_16x16x32_bf16(a0[mi], bb0[ni], acc[mi][ni], 0, 0, 0);
        acc[mi][ni] = __builtin_amdgcn_mfma_f32_16x16x32_bf16(a1[mi], bb1[ni], acc[mi][ni], 0, 0, 0);
      }
  }
  float* dst = ls + (nq >> 1) * (64 * 65);
#pragma unroll
  for (int mi = 0; mi < 2; ++mi)
#pragma unroll
    for (int ni = 0; ni < 2; ++ni)
#pragma unroll
      for (int r = 0; r < 4; ++r) {
        const int rl = mi2 * 32 + mi * 16 + lq * 4 + r;
        const int cl = (nq & 1) * 32 + ni * 16 + l15;
        dst[rl * 65 + cl] = acc[mi][ni][r];
      }
  __syncthreads();
#pragma unroll
  for (int i = 0; i < 8; ++i) {
    const int e = tid + i * 512;
    const int r = e >> 6, c = e & 63;
    const long b = b0 + r;
    const int j = j0 + c;
    const float f1 = tanh_f(ls[r * 65 + c] + bf1[j]);
    const float zc = ls[64 * 65 + r * 65 + c];
    const long pr = (b * NS_ + s) * 1024;
    const float f2 = tanh_f(bf2f(FZpre[pr + j]));
    const float z = sigm_f(zc + bf2f(FZpre[pr + 512 + j]));
    const float I = z * f1 + (1.f - z) * f2;
    Char_out[(b * NS_ + s) * 512 + j] = I;
    Ichar[b * 512 + j] = f2bf(I);
  }
}

__global__ __launch_bounds__(512) void gates_lstm_k(
    const unsigned short* __restrict__ Ichar, const unsigned short* __restrict__ embb,
    const unsigned short* __restrict__ WihE, const float* __restrict__ hpgh,
    float* __restrict__ cbuf, float* __restrict__ hid_out,
    unsigned short* __restrict__ hwr, int s) {
  __shared__ float gs[4 * 32 * 65];
  const int tid = threadIdx.x, w = tid >> 6, l = tid & 63, l15 = l & 15, lq = l >> 4;
  const int b0 = blockIdx.y * 32, j0 = blockIdx.x * 64;
  const int g = w & 3, mi = w >> 2;
  const long arow = b0 + mi * 16 + l15;
  f32x4 acc[4] = {};
  for (int kt = 0; kt < 768; kt += 64) {
    const int k0 = kt + lq * 8, k1 = k0 + 32;
    bf16x8 a0, a1, b0r[4], b1r[4];
    a0 = (k0 < 512) ? *(const bf16x8*)(Ichar + arow * 512 + k0)
                    : *(const bf16x8*)(embb + (arow * NS_ + s) * 256 + (k0 - 512));
    a1 = (k1 < 512) ? *(const bf16x8*)(Ichar + arow * 512 + k1)
                    : *(const bf16x8*)(embb + (arow * NS_ + s) * 256 + (k1 - 512));
#pragma unroll
    for (int ni = 0; ni < 4; ++ni) {
      const long wrow = g * 512 + j0 + ni * 16 + l15;
      b0r[ni] = *(const bf16x8*)(WihE + wrow * 768 + k0);
      b1r[ni] = *(const bf16x8*)(WihE + wrow * 768 + k1);
    }
#pragma unroll
    for (int ni = 0; ni < 4; ++ni) {
      acc[ni] = __builtin_amdgcn_mfma_f32_16x16x32_bf16(a0, b0r[ni], acc[ni], 0, 0, 0);
      acc[ni] = __builtin_amdgcn_mfma_f32_16x16x32_bf16(a1, b1r[ni], acc[ni], 0, 0, 0);
    }
  }
#pragma unroll
  for (int ni = 0; ni < 4; ++ni)
#pragma unroll
    for (int r = 0; r < 4; ++r) {
      const int rl = mi * 16 + lq * 4 + r;
      const int cl = ni * 16 + l15;
      gs[(g * 32 + rl) * 65 + cl] = acc[ni][r];
    }
  __syncthreads();
#pragma unroll
  for (int i = 0; i < 4; ++i) {
    const int e = tid + i * 512;
    const int r = e >> 6, c = e & 63;
    const long b = b0 + r;
    const int j = j0 + c;
    const float* ggh = hpgh + b * 2560 + 512;
    const float ig = sigm_f(gs[(0 * 32 + r) * 65 + c] + ggh[j]);
    const float fg = sigm_f(gs[(1 * 32 + r) * 65 + c] + ggh[512 + j]);
    const float gg = tanh_f(gs[(2 * 32 + r) * 65 + c] + ggh[1024 + j]);
    const float og = sigm_f(gs[(3 * 32 + r) * 65 + c] + ggh[1536 + j]);
    const float cn = fg * cbuf[b * 512 + j] + ig * gg;
    cbuf[b * 512 + j] = cn;
    const float h = og * tanh_f(cn);
    hid_out[(b * NS_ + s) * 512 + j] = h;
    hwr[b * 512 + j] = f2bf(h);
  }
}

__global__ __launch_bounds__(256) void probs_k(
    const float* __restrict__ Af, const unsigned short* __restrict__ Wg,
    const float* __restrict__ bias, float* __restrict__ outp) {
  const int tid = threadIdx.x, w = tid >> 6, l = tid & 63, l15 = l & 15, lq = l >> 4;
  const long mrow = (long)blockIdx.y * 64 + w * 16 + l15;
  const int nbase = blockIdx.x * 64;
  f32x4 acc[4] = {};
  for (int kt = 0; kt < 512; kt += 32) {
    const int k = kt + lq * 8;
    const float4 av0 = *(const float4*)(Af + mrow * 512 + k);
    const float4 av1 = *(const float4*)(Af + mrow * 512 + k + 4);
    bf16x8 a;
    a[0] = (short)f2bf(av0.x); a[1] = (short)f2bf(av0.y);
    a[2] = (short)f2bf(av0.z); a[3] = (short)f2bf(av0.w);
    a[4] = (short)f2bf(av1.x); a[5] = (short)f2bf(av1.y);
    a[6] = (short)f2bf(av1.z); a[7] = (short)f2bf(av1.w);
#pragma unroll
    for (int nb = 0; nb < 4; ++nb) {
      const bf16x8 b = *(const bf16x8*)(Wg + (long)(nbase + nb * 16 + l15) * 512 + k);
      acc[nb] = __builtin_amdgcn_mfma_f32_16x16x32_bf16(a, b, acc[nb], 0, 0, 0);
    }
  }
#pragma unroll
  for (int nb = 0; nb < 4; ++nb) {
    const int colg = nbase + nb * 16 + l15;
    if (colg >= NCLS_) continue;
    const float bv = bias[colg];
#pragma unroll
    for (int r = 0; r < 4; ++r) {
      const long rowg = (long)blockIdx.y * 64 + w * 16 + lq * 4 + r;
      outp[rowg * NCLS_ + colg] = acc[nb][r] + bv;
    }
  }
}

// ============ prologue helpers ============
__global__ void cvt_f32_bf16_k(const float* __restrict__ in, unsigned short* __restrict__ out, long n) {
  const long i = ((long)blockIdx.x * 256 + threadIdx.x) * 4;
  if (i + 4 <= n) {
    const float4 v = *(const float4*)(in + i);
    ushort4 o;
    o.x = f2bf(v.x); o.y = f2bf(v.y); o.z = f2bf(v.z); o.w = f2bf(v.w);
    *(ushort4*)(out + i) = o;
  }
}

__global__ void embed_k(const float* __restrict__ emb_table, const int* __restrict__ text,
                        unsigned short* __restrict__ out) {
  const int bs = blockIdx.x, j = threadIdx.x;
  const int t = text[bs];
  out[(long)bs * 256 + j] = f2bf(emb_table[(long)t * 256 + j]);
}

__global__ void pack_WA_k(const float* __restrict__ W_h2h, const float* __restrict__ W_hh,
                          unsigned short* __restrict__ out) {
  const long idx = (long)blockIdx.x * 256 + threadIdx.x;
  const int row = (int)(idx >> 9), k = (int)(idx & 511);
  const float v = (row < 512) ? W_h2h[(long)row * 512 + k] : W_hh[(long)(row - 512) * 512 + k];
  out[idx] = f2bf(v);
}

__global__ void pack_wfz_k(const float* __restrict__ Wf, const float* __restrict__ Wz, int zoff,
                           unsigned short* __restrict__ out) {
  const long idx = (long)blockIdx.x * 256 + threadIdx.x;
  const int row = (int)(idx >> 9), k = (int)(idx & 511);
  const float v = (row < 512) ? Wf[(long)row * 512 + k]
                              : Wz[(long)(row - 512) * 1024 + zoff + k];
  out[idx] = f2bf(v);
}

__global__ void pack_Wgen_k(const float* __restrict__ W_gen, unsigned short* __restrict__ out) {
  const long idx = (long)blockIdx.x * 256 + threadIdx.x;  // 128*512
  const int row = (int)(idx >> 9), k = (int)(idx & 511);
  out[idx] = (row < NCLS_) ? f2bf(W_gen[(long)row * 512 + k]) : (unsigned short)0;
}

__global__ void pack_bias_k(const float* __restrict__ b_h2h, const float* __restrict__ b_ih,
                            const float* __restrict__ b_hh, const float* __restrict__ bf2,
                            const float* __restrict__ bz,
                            float* __restrict__ biasA, float* __restrict__ biasFZ) {
  const int i = blockIdx.x * 256 + threadIdx.x;  // 3584
  if (i < 2560) {
    biasA[i] = (i < 512) ? b_h2h[i] : (b_ih[i - 512] + b_hh[i - 512]);
  } else {
    const int j = i - 2560;
    biasFZ[j] = (j < 512) ? bf2[j] : bz[j - 512];
  }
}

extern "C" void kernel_launch(void* const* d_in, const int* in_sizes, int n_in,
                              void* d_out, int out_size, void* d_ws, size_t ws_size,
                              hipStream_t stream) {
  (void)in_sizes; (void)n_in; (void)out_size; (void)ws_size;
  const float* batch_H  = (const float*)d_in[0];
  const float* AS       = (const float*)d_in[1];
  const int*   text     = (const int*)d_in[2];
  const float* W_i2h    = (const float*)d_in[3];
  const float* W_h2h    = (const float*)d_in[4];
  const float* b_h2h    = (const float*)d_in[5];
  const float* w_score  = (const float*)d_in[6];
  const float* W_ih     = (const float*)d_in[7];
  const float* W_hh     = (const float*)d_in[8];
  const float* b_ih     = (const float*)d_in[9];
  const float* b_hh     = (const float*)d_in[10];
  const float* Wf1      = (const float*)d_in[11];
  const float* bf1      = (const float*)d_in[12];
  const float* Wf2      = (const float*)d_in[13];
  const float* bf2      = (const float*)d_in[14];
  const float* Wz       = (const float*)d_in[15];
  const float* bz       = (const float*)d_in[16];
  const float* W_gen    = (const float*)d_in[17];
  const float* b_gen    = (const float*)d_in[18];
  const float* emb_tab  = (const float*)d_in[19];

  float* out = (float*)d_out;
  float* out_probs = out;                       // [B,NS,NCLS]
  float* out_attn  = out + 1291264;             // [B,T,NS]
  float* out_hid   = out + 2143232;             // [B,NS,H]
  float* out_char  = out + 8958976;             // [B,NS,H]

  char* wsp = (char*)d_ws;
  auto alloc = [&](size_t bytes) { char* p = wsp; wsp += (bytes + 255) & ~(size_t)255; return p; };
  unsigned short* bH    = (unsigned short*)alloc(33554432);  // [B,T,C] bf16
  unsigned short* Hproj = (unsigned short*)alloc(33554432);  // [B,T,H] bf16
  unsigned short* ASb   = (unsigned short*)alloc(13631488);  // [B*NS,512] bf16 (prologue only)
  unsigned short* embb  = (unsigned short*)alloc(6815744);   // [B,NS,NEMB] bf16
  unsigned short* FZpre = (unsigned short*)alloc(27262976);  // [B*NS,1024] bf16
  unsigned short* WA    = (unsigned short*)alloc(2621440);   // [2560,512]
  unsigned short* Wfz   = (unsigned short*)alloc(1048576);   // [1024,512]  (Wf1 | Wz-left)
  unsigned short* Wfz2  = (unsigned short*)alloc(1048576);   // [1024,512]  (Wf2 | Wz-right)
  unsigned short* WihE  = (unsigned short*)alloc(3145728);   // [2048,768]
  unsigned short* Wgenb = (unsigned short*)alloc(131072);    // [128,512]
  unsigned short* Wi2hb = (unsigned short*)alloc(524288);    // [512,512]
  float* biasA          = (float*)alloc(10240);              // [2560]
  float* biasFZ         = (float*)alloc(4096);               // [1024]
  // ---- aliased into ASb (dead after FZpre GEMM) ----
  char* ab = (char*)ASb;
  float* hpgh           = (float*)(ab);                      // [512,2560] f32 (5242880)
  unsigned short* ctx   = (unsigned short*)(ab + 5242880);   // [B,512] bf16 (524288)
  unsigned short* Ichar = (unsigned short*)(ab + 5767168);   // [B,512] bf16 (524288)
  float* cbuf           = (float*)(ab + 6291456);            // [B,512] f32 (1048576)
  unsigned short* hbuf  = (unsigned short*)(ab + 7340032);   // 2x [B,512] bf16 (1048576)

  // -------- prologue --------
  cvt_f32_bf16_k<<<dim3(16384), dim3(256), 0, stream>>>(batch_H, bH, 16777216);
  cvt_f32_bf16_k<<<dim3(6656), dim3(256), 0, stream>>>(AS, ASb, 6815744);
  cvt_f32_bf16_k<<<dim3(256), dim3(256), 0, stream>>>(W_i2h, Wi2hb, 262144);
  cvt_f32_bf16_k<<<dim3(1536), dim3(256), 0, stream>>>(W_ih, WihE, 1572864);
  embed_k<<<dim3(13312), dim3(256), 0, stream>>>(emb_tab, text, embb);
  pack_WA_k<<<dim3(5120), dim3(256), 0, stream>>>(W_h2h, W_hh, WA);
  pack_wfz_k<<<dim3(2048), dim3(256), 0, stream>>>(Wf1, Wz, 0, Wfz);
  pack_wfz_k<<<dim3(2048), dim3(256), 0, stream>>>(Wf2, Wz, 512, Wfz2);
  pack_Wgen_k<<<dim3(256), dim3(256), 0, stream>>>(W_gen, Wgenb);
  pack_bias_k<<<dim3(14), dim3(256), 0, stream>>>(b_h2h, b_ih, b_hh, bf2, bz, biasA, biasFZ);

  // H_proj = batch_H @ W_i2h^T  (M=32768, N=512, K=512) -> bf16
  gemm_tiled_k<false><<<dim3(4, 256), dim3(256), 0, stream>>>(
      bH, Wi2hb, nullptr, nullptr, Hproj, 512, 512, 512);

  // FZpre = AS @ [Wf2 | Wz-right]^T + [bf2 | bz]  (M=13312, N=1024, K=512) -> bf16
  gemm_tiled_k<false><<<dim3(8, 104), dim3(256), 0, stream>>>(
      ASb, Wfz2, biasFZ, nullptr, FZpre, 512, 1024, 1024);

  // ASb region dead -> init aliased state buffers
  hipMemsetAsync(cbuf, 0, 1048576, stream);
  hipMemsetAsync(hbuf, 0, 1048576, stream);

  // -------- cooperative 26-step scan + probs (256 blocks x 1024 thr = 16 waves/CU) --------
  CoopArgs ca;
  ca.Hproj = Hproj; ca.bH = bH; ca.WA = WA; ca.Wfz = Wfz; ca.FZpre = FZpre;
  ca.WihE = WihE; ca.embb = embb; ca.Wgenb = Wgenb;
  ca.biasA = biasA; ca.w_score = w_score; ca.bf1 = bf1; ca.b_gen = b_gen;
  ca.hpgh = hpgh; ca.out_attn = out_attn; ca.out_char = out_char;
  ca.out_hid = out_hid; ca.out_probs = out_probs; ca.cbuf = cbuf;
  ca.ctx = ctx; ca.Ichar = Ichar; ca.hbuf = hbuf;
  void* kargs[] = { (void*)&ca };
  hipError_t cerr = hipLaunchCooperativeKernel((const void*)scan_coop_k, dim3(256), dim3(1024),
                                               kargs, 0, stream);
  if (cerr != hipSuccess) {
    // -------- fallback: proven multi-kernel path --------
    for (int s = 0; s < NS_; ++s) {
      unsigned short* hrd = hbuf + (s & 1) * 262144;
      unsigned short* hwr = hbuf + ((s + 1) & 1) * 262144;
      gemm_hpgh_k<<<dim3(40, 8), dim3(256), 0, stream>>>(hrd, WA, biasA, hpgh);
      attn_step_k<<<dim3(512), dim3(512), 0, stream>>>(Hproj, bH, hpgh, w_score, out_attn, ctx, s);
      gated_fused_k<<<dim3(8, 8), dim3(512), 0, stream>>>(
          ctx, Wfz, FZpre, bf1, Ichar, out_char, s);
      gates_lstm_k<<<dim3(8, 16), dim3(512), 0, stream>>>(
          Ichar, embb, WihE, hpgh, cbuf, out_hid, hwr, s);
    }
    probs_k<<<dim3(2, 208), dim3(256), 0, stream>>>(out_hid, Wgenb, b_gen, out_probs);
  }
}

// Round 8
// 3586.602 us; speedup vs baseline: 1.5100x; 1.4250x over previous
//
#include <hip/hip_runtime.h>

#define NS_ 26
#define NCLS_ 97

typedef short bf16x8 __attribute__((ext_vector_type(8)));
typedef float f32x4 __attribute__((ext_vector_type(4)));

__device__ __forceinline__ unsigned short f2bf(float f) {
  union { float f; unsigned u; } v; v.f = f;
  unsigned r = v.u + 0x7fffu + ((v.u >> 16) & 1u);
  return (unsigned short)(r >> 16);
}
__device__ __forceinline__ float bf2f(unsigned short h) {
  union { unsigned u; float f; } v; v.u = ((unsigned)h) << 16;
  return v.f;
}
__device__ __forceinline__ float sigm_f(float x) { return 1.f / (1.f + __expf(-x)); }
__device__ __forceinline__ float tanh_f(float x) { return 1.f - 2.f / (1.f + __expf(2.f * x)); }

__device__ __forceinline__ void gl_lds16(const void* g, void* l) {
  __builtin_amdgcn_global_load_lds(
      (const __attribute__((address_space(1))) unsigned int*)g,
      (__attribute__((address_space(3))) unsigned int*)l, 16, 0, 0);
}

// group barrier: 32 blocks, monotone arrival counter + generation word.
__device__ __forceinline__ void gbar(unsigned* bar, unsigned* gen, unsigned target) {
  __syncthreads();
  if (threadIdx.x == 0) {
    __threadfence();
    const unsigned prev = __hip_atomic_fetch_add(bar, 1u, __ATOMIC_RELAXED, __HIP_MEMORY_SCOPE_AGENT);
    if (prev + 1u == target * 32u) {
      __hip_atomic_store(gen, target, __ATOMIC_RELEASE, __HIP_MEMORY_SCOPE_AGENT);
    } else {
      while (__hip_atomic_load(gen, __ATOMIC_RELAXED, __HIP_MEMORY_SCOPE_AGENT) < target) {}
    }
    __threadfence();
  }
  __syncthreads();
}

// ============ tiled 128x128 GEMM (prologue) ============
template <bool OUTF>
__global__ __launch_bounds__(256) void gemm_tiled_k(
    const unsigned short* __restrict__ Ag, const unsigned short* __restrict__ Bg,
    const float* __restrict__ bias, float* __restrict__ outF,
    unsigned short* __restrict__ outB, int K, long ldo, int Nvalid) {
  __shared__ unsigned short As[128 * 64];
  __shared__ unsigned short Bs[128 * 64];
  const int tid = threadIdx.x;
  const int w = tid >> 6, l = tid & 63;
  const int l15 = l & 15, lq = l >> 4;
  const int wm = w >> 1, wn = w & 1;
  const long rowBase = (long)blockIdx.y * 128;
  const long colBase = (long)blockIdx.x * 128;
  const int lrow = l >> 3, ps_st = l & 7;
  f32x4 acc[4][4] = {};
  for (int kt = 0; kt < K; kt += 64) {
#pragma unroll
    for (int i = 0; i < 4; ++i) {
      const int row = i * 32 + w * 8 + lrow;
      const int ls = ps_st ^ (row & 7);
      gl_lds16(Ag + (rowBase + row) * K + kt + ls * 8, As + i * 2048 + w * 512);
      gl_lds16(Bg + (colBase + row) * K + kt + ls * 8, Bs + i * 2048 + w * 512);
    }
    __syncthreads();
#pragma unroll
    for (int kh = 0; kh < 2; ++kh) {
      bf16x8 af[4], bfr[4];
#pragma unroll
      for (int mi = 0; mi < 4; ++mi) {
        const int row = wm * 64 + mi * 16 + l15;
        const int ps = (kh * 4 + lq) ^ (row & 7);
        af[mi] = *(const bf16x8*)(As + row * 64 + ps * 8);
      }
#pragma unroll
      for (int ni = 0; ni < 4; ++ni) {
        const int row = wn * 64 + ni * 16 + l15;
        const int ps = (kh * 4 + lq) ^ (row & 7);
        bfr[ni] = *(const bf16x8*)(Bs + row * 64 + ps * 8);
      }
#pragma unroll
      for (int mi = 0; mi < 4; ++mi)
#pragma unroll
        for (int ni = 0; ni < 4; ++ni)
          acc[mi][ni] = __builtin_amdgcn_mfma_f32_16x16x32_bf16(af[mi], bfr[ni], acc[mi][ni], 0, 0, 0);
    }
    __syncthreads();
  }
#pragma unroll
  for (int mi = 0; mi < 4; ++mi)
#pragma unroll
    for (int ni = 0; ni < 4; ++ni) {
      const long gcol = colBase + wn * 64 + ni * 16 + l15;
      if (gcol >= Nvalid) continue;
      const float bv = bias ? bias[gcol] : 0.f;
#pragma unroll
      for (int r = 0; r < 4; ++r) {
        const long grow = rowBase + wm * 64 + mi * 16 + lq * 4 + r;
        const float v = acc[mi][ni][r] + bv;
        if (OUTF) outF[grow * ldo + gcol] = v;
        else      outB[grow * ldo + gcol] = f2bf(v);
      }
    }
}

// ============ persistent scan kernel: 256 blocks x 1024 thr, 8 groups x 32 blocks ============
struct CoopArgs {
  const unsigned short* Hproj;   // [B,64,512] bf16
  const unsigned short* bH;      // [B,64,512] bf16
  const unsigned short* WA;      // [2560,512] bf16
  const unsigned short* Wfz;     // [1024,512] bf16 (Wf1 | Wz-left)
  const unsigned short* FZpre;   // [B*NS,1024] bf16
  const unsigned short* WihE;    // [2048,768] bf16
  const unsigned short* embb;    // [B,NS,256] bf16
  const unsigned short* Wgenb;   // [128,512] bf16
  const float* biasA;            // [2560]
  const float* w_score;          // [512]
  const float* bf1;              // [512]
  const float* b_gen;            // [97]
  float* hpgh;                   // [512,2560]
  float* out_attn;               // [B,64,NS]
  float* out_char;               // [B,NS,512]
  float* out_hid;                // [B,NS,512]
  float* out_probs;              // [B*NS,97]
  float* cbuf;                   // [B,512]
  unsigned short* ctx;           // [B,512] bf16
  unsigned short* Ichar;         // [B,512] bf16
  unsigned short* hbuf;          // 2x [B,512] bf16
  unsigned* bars;                // 8 groups x 32 uints (bar, gen)
};

__global__ __launch_bounds__(1024, 4) void scan_coop_k(CoopArgs A) {
  __shared__ float smem[4872];   // [0..4352) phase scratch; [4352..4872) ws_t (stride 65)
  float* ws_t = smem + 4352;
  const int tid = threadIdx.x;
  const int sb = tid >> 8;           // sub-block 0..3
  const int stid = tid & 255;
  const int sw = stid >> 6;          // wave in sub-block 0..3
  const int l = tid & 63, l15 = l & 15, lq = l >> 4;
  const int bx = blockIdx.x;
  const int g = bx & 7;              // group (XCD round-robin heuristic)
  const int lb = bx >> 3;            // local block 0..31
  unsigned* bar = A.bars + g * 32;
  unsigned* gen = bar + 1;
  unsigned tgt = 0;
  const int u4 = lb * 4 + sb;        // sub-block slot 0..127 within group
  const long rb = (long)g * 64;      // group row base

  if (tid < 512) ws_t[(tid & 7) * 65 + (tid >> 3)] = A.w_score[tid];
  __syncthreads();

  for (int s = 0; s < NS_; ++s) {
    const unsigned short* hrd = A.hbuf + (s & 1) * 262144;
    unsigned short* hwr = A.hbuf + ((s + 1) & 1) * 262144;

    // ---- P1: hpgh[rb..rb+64, :2560] = h @ WA^T + biasA  (80 units of 64r x 32c) ----
    if (u4 < 80) {
      const int nbase = u4 * 32;
      const long mrow = rb + sw * 16 + l15;
      f32x4 acc[2] = {};
      for (int kt = 0; kt < 512; kt += 64) {
        const int k0 = kt + lq * 8, k1 = k0 + 32;
        const bf16x8 a0 = *(const bf16x8*)(hrd + mrow * 512 + k0);
        const bf16x8 a1 = *(const bf16x8*)(hrd + mrow * 512 + k1);
        bf16x8 b0[2], b1[2];
#pragma unroll
        for (int ni = 0; ni < 2; ++ni) {
          const long wr = nbase + ni * 16 + l15;
          b0[ni] = *(const bf16x8*)(A.WA + wr * 512 + k0);
          b1[ni] = *(const bf16x8*)(A.WA + wr * 512 + k1);
        }
#pragma unroll
        for (int ni = 0; ni < 2; ++ni) {
          acc[ni] = __builtin_amdgcn_mfma_f32_16x16x32_bf16(a0, b0[ni], acc[ni], 0, 0, 0);
          acc[ni] = __builtin_amdgcn_mfma_f32_16x16x32_bf16(a1, b1[ni], acc[ni], 0, 0, 0);
        }
      }
#pragma unroll
      for (int ni = 0; ni < 2; ++ni) {
        const int colg = nbase + ni * 16 + l15;
        const float bv = A.biasA[colg];
#pragma unroll
        for (int r = 0; r < 4; ++r) {
          const long rowg = rb + sw * 16 + lq * 4 + r;
          A.hpgh[rowg * 2560 + colg] = acc[ni][r] + bv;
        }
      }
    }
    gbar(bar, gen, ++tgt);

    // ---- P2: attention — 2 rows per block (512-thr row-teams) ----
    {
      const int ssb = tid >> 9;          // row-team 0/1
      const int sstid = tid & 511;
      const long b = rb + lb * 2 + ssb;
      float* S = smem + ssb * 1100;      // hp_t[520] | e[64] | csum[512]
      S[(sstid & 7) * 65 + (sstid >> 3)] = A.hpgh[b * 2560 + sstid];
      __syncthreads();
      const int w8 = sstid >> 6;
      float* e_s = S + 520;
#pragma unroll
      for (int tt = 0; tt < 8; ++tt) {
        const int t = w8 * 8 + tt;
        const bf16x8 hv = *(const bf16x8*)(A.Hproj + (b * 64 + t) * 512 + l * 8);
        float acc = 0.f;
#pragma unroll
        for (int j = 0; j < 8; ++j)
          acc += tanh_f(bf2f((unsigned short)hv[j]) + S[j * 65 + l]) * ws_t[j * 65 + l];
        acc += __shfl_xor(acc, 1);
        acc += __shfl_xor(acc, 2);
        acc += __shfl_xor(acc, 4);
        acc += __shfl_xor(acc, 8);
        acc += __shfl_xor(acc, 16);
        acc += __shfl_xor(acc, 32);
        if (l == 0) e_s[t] = acc;
      }
      __syncthreads();
      if (sstid < 64) {
        const float e = e_s[sstid];
        float m = e;
        for (int off = 32; off; off >>= 1) m = fmaxf(m, __shfl_xor(m, off));
        const float p = __expf(e - m);
        float sum = p;
        for (int off = 32; off; off >>= 1) sum += __shfl_xor(sum, off);
        const float al = p / sum;
        e_s[sstid] = al;
        A.out_attn[(b * 64 + sstid) * NS_ + s] = al;
      }
      __syncthreads();
      const int half = sstid >> 8, jj = sstid & 255;
      float c0 = 0.f, c1 = 0.f;
      const unsigned* bhp = (const unsigned*)(A.bH + (b * 64 + half * 32) * 512) + jj;
#pragma unroll 8
      for (int t = 0; t < 32; ++t) {
        const float al = e_s[half * 32 + t];
        const unsigned pv = bhp[(long)t * 256];
        c0 += al * bf2f((unsigned short)(pv & 0xffffu));
        c1 += al * bf2f((unsigned short)(pv >> 16));
      }
      float* csum = S + 584;
      if (half) { csum[jj * 2] = c0; csum[jj * 2 + 1] = c1; }
      __syncthreads();
      if (!half) {
        c0 += csum[jj * 2];
        c1 += csum[jj * 2 + 1];
        ((unsigned*)A.ctx)[b * 256 + jj] = (unsigned)f2bf(c0) | ((unsigned)f2bf(c1) << 16);
      }
    }
    gbar(bar, gen, ++tgt);

    // ---- P3: gated fusion (64 units of 16r x 32c; wave=(which,colhalf)) ----
    {
      const bool act = u4 < 64;
      int j0 = 0;
      long b0 = rb;
      if (act) {
        j0 = (u4 & 15) * 32;
        b0 = rb + (u4 >> 4) * 16;
        const int which = sw >> 1, nh = sw & 1;
        f32x4 acc = {};
        const long arow = b0 + l15;
        const long gw = (long)(which ? 512 : 0) + j0 + nh * 16 + l15;
        for (int kt = 0; kt < 512; kt += 64) {
          const int k0 = kt + lq * 8, k1 = k0 + 32;
          const bf16x8 a0 = *(const bf16x8*)(A.ctx + arow * 512 + k0);
          const bf16x8 a1 = *(const bf16x8*)(A.ctx + arow * 512 + k1);
          const bf16x8 w0 = *(const bf16x8*)(A.Wfz + gw * 512 + k0);
          const bf16x8 w1 = *(const bf16x8*)(A.Wfz + gw * 512 + k1);
          acc = __builtin_amdgcn_mfma_f32_16x16x32_bf16(a0, w0, acc, 0, 0, 0);
          acc = __builtin_amdgcn_mfma_f32_16x16x32_bf16(a1, w1, acc, 0, 0, 0);
        }
        float* S = smem + sb * 1088;
#pragma unroll
        for (int r = 0; r < 4; ++r)
          S[which * 528 + (lq * 4 + r) * 33 + nh * 16 + l15] = acc[r];
      }
      __syncthreads();
      if (act) {
        const float* S = smem + sb * 1088;
#pragma unroll
        for (int i = 0; i < 2; ++i) {
          const int e = stid + i * 256;
          const int r = e >> 5, c = e & 31;
          const long b = b0 + r;
          const int j = j0 + c;
          const float f1 = tanh_f(S[r * 33 + c] + A.bf1[j]);
          const float zc = S[528 + r * 33 + c];
          const long pr = (b * NS_ + s) * 1024;
          const float f2 = tanh_f(bf2f(A.FZpre[pr + j]));
          const float z = sigm_f(zc + bf2f(A.FZpre[pr + 512 + j]));
          const float I = z * f1 + (1.f - z) * f2;
          A.out_char[(b * NS_ + s) * 512 + j] = I;
          A.Ichar[b * 512 + j] = f2bf(I);
        }
      }
    }
    gbar(bar, gen, ++tgt);

    // ---- P4: gates GEMM + LSTM (128 units of 16r x 16c; wave = gate) ----
    {
      const int j0 = (u4 & 31) * 16;
      const long b0 = rb + (u4 >> 5) * 16;
      const int gg4 = sw;
      f32x4 acc = {};
      const long arow = b0 + l15;
      const long wrow = (long)gg4 * 512 + j0 + l15;
      for (int kt = 0; kt < 768; kt += 64) {
        const int k0 = kt + lq * 8, k1 = k0 + 32;
        const bf16x8 a0 = (k0 < 512)
            ? *(const bf16x8*)(A.Ichar + arow * 512 + k0)
            : *(const bf16x8*)(A.embb + (arow * NS_ + s) * 256 + (k0 - 512));
        const bf16x8 a1 = (k1 < 512)
            ? *(const bf16x8*)(A.Ichar + arow * 512 + k1)
            : *(const bf16x8*)(A.embb + (arow * NS_ + s) * 256 + (k1 - 512));
        const bf16x8 w0 = *(const bf16x8*)(A.WihE + wrow * 768 + k0);
        const bf16x8 w1 = *(const bf16x8*)(A.WihE + wrow * 768 + k1);
        acc = __builtin_amdgcn_mfma_f32_16x16x32_bf16(a0, w0, acc, 0, 0, 0);
        acc = __builtin_amdgcn_mfma_f32_16x16x32_bf16(a1, w1, acc, 0, 0, 0);
      }
      float* S = smem + sb * 1088;
#pragma unroll
      for (int r = 0; r < 4; ++r)
        S[gg4 * 272 + (lq * 4 + r) * 17 + l15] = acc[r];
      __syncthreads();
      {
        const float* S2 = smem + sb * 1088;
        const int r = stid >> 4, c = stid & 15;
        const long b = b0 + r;
        const int j = j0 + c;
        const float* ggh = A.hpgh + b * 2560 + 512;
        const float ig = sigm_f(S2[r * 17 + c] + ggh[j]);
        const float fg = sigm_f(S2[272 + r * 17 + c] + ggh[512 + j]);
        const float gv = tanh_f(S2[544 + r * 17 + c] + ggh[1024 + j]);
        const float og = sigm_f(S2[816 + r * 17 + c] + ggh[1536 + j]);
        const float cn = fg * A.cbuf[b * 512 + j] + ig * gv;
        A.cbuf[b * 512 + j] = cn;
        const float h = og * tanh_f(cn);
        A.out_hid[(b * NS_ + s) * 512 + j] = h;
        hwr[b * 512 + j] = f2bf(h);
      }
    }
    gbar(bar, gen, ++tgt);
  }

  // ---- P5: probs for group rows (52 units of 64x64; rows g*1664..+1664) ----
  if (u4 < 52) {
    const int rt = u4 >> 1, jt = u4 & 1;
    const int nbase = jt * 64;
    const long mrow = (long)g * 1664 + rt * 64 + sw * 16 + l15;
    f32x4 acc[4] = {};
    for (int kt = 0; kt < 512; kt += 32) {
      const int k = kt + lq * 8;
      const float4 av0 = *(const float4*)(A.out_hid + mrow * 512 + k);
      const float4 av1 = *(const float4*)(A.out_hid + mrow * 512 + k + 4);
      bf16x8 a;
      a[0] = (short)f2bf(av0.x); a[1] = (short)f2bf(av0.y);
      a[2] = (short)f2bf(av0.z); a[3] = (short)f2bf(av0.w);
      a[4] = (short)f2bf(av1.x); a[5] = (short)f2bf(av1.y);
      a[6] = (short)f2bf(av1.z); a[7] = (short)f2bf(av1.w);
#pragma unroll
      for (int nb = 0; nb < 4; ++nb) {
        const bf16x8 b = *(const bf16x8*)(A.Wgenb + (long)(nbase + nb * 16 + l15) * 512 + k);
        acc[nb] = __builtin_amdgcn_mfma_f32_16x16x32_bf16(a, b, acc[nb], 0, 0, 0);
      }
    }
#pragma unroll
    for (int nb = 0; nb < 4; ++nb) {
      const int colg = nbase + nb * 16 + l15;
      if (colg >= NCLS_) continue;
      const float bv = A.b_gen[colg];
#pragma unroll
      for (int r = 0; r < 4; ++r) {
        const long rowg = (long)g * 1664 + rt * 64 + sw * 16 + lq * 4 + r;
        A.out_probs[rowg * NCLS_ + colg] = acc[nb][r] + bv;
      }
    }
  }
}

// ============ prologue helpers ============
__global__ void cvt_f32_bf16_k(const float* __restrict__ in, unsigned short* __restrict__ out, long n) {
  const long i = ((long)blockIdx.x * 256 + threadIdx.x) * 4;
  if (i + 4 <= n) {
    const float4 v = *(const float4*)(in + i);
    ushort4 o;
    o.x = f2bf(v.x); o.y = f2bf(v.y); o.z = f2bf(v.z); o.w = f2bf(v.w);
    *(ushort4*)(out + i) = o;
  }
}

__global__ void embed_k(const float* __restrict__ emb_table, const int* __restrict__ text,
                        unsigned short* __restrict__ out) {
  const int bs = blockIdx.x, j = threadIdx.x;
  const int t = text[bs];
  out[(long)bs * 256 + j] = f2bf(emb_table[(long)t * 256 + j]);
}

__global__ void pack_WA_k(const float* __restrict__ W_h2h, const float* __restrict__ W_hh,
                          unsigned short* __restrict__ out) {
  const long idx = (long)blockIdx.x * 256 + threadIdx.x;
  const int row = (int)(idx >> 9), k = (int)(idx & 511);
  const float v = (row < 512) ? W_h2h[(long)row * 512 + k] : W_hh[(long)(row - 512) * 512 + k];
  out[idx] = f2bf(v);
}

__global__ void pack_wfz_k(const float* __restrict__ Wf, const float* __restrict__ Wz, int zoff,
                           unsigned short* __restrict__ out) {
  const long idx = (long)blockIdx.x * 256 + threadIdx.x;
  const int row = (int)(idx >> 9), k = (int)(idx & 511);
  const float v = (row < 512) ? Wf[(long)row * 512 + k]
                              : Wz[(long)(row - 512) * 1024 + zoff + k];
  out[idx] = f2bf(v);
}

__global__ void pack_Wgen_k(const float* __restrict__ W_gen, unsigned short* __restrict__ out) {
  const long idx = (long)blockIdx.x * 256 + threadIdx.x;  // 128*512
  const int row = (int)(idx >> 9), k = (int)(idx & 511);
  out[idx] = (row < NCLS_) ? f2bf(W_gen[(long)row * 512 + k]) : (unsigned short)0;
}

__global__ void pack_bias_k(const float* __restrict__ b_h2h, const float* __restrict__ b_ih,
                            const float* __restrict__ b_hh, const float* __restrict__ bf2,
                            const float* __restrict__ bz,
                            float* __restrict__ biasA, float* __restrict__ biasFZ) {
  const int i = blockIdx.x * 256 + threadIdx.x;  // 3584
  if (i < 2560) {
    biasA[i] = (i < 512) ? b_h2h[i] : (b_ih[i - 512] + b_hh[i - 512]);
  } else {
    const int j = i - 2560;
    if (j < 1024) biasFZ[j] = (j < 512) ? bf2[j] : bz[j - 512];
  }
}

extern "C" void kernel_launch(void* const* d_in, const int* in_sizes, int n_in,
                              void* d_out, int out_size, void* d_ws, size_t ws_size,
                              hipStream_t stream) {
  (void)in_sizes; (void)n_in; (void)out_size; (void)ws_size;
  const float* batch_H  = (const float*)d_in[0];
  const float* AS       = (const float*)d_in[1];
  const int*   text     = (const int*)d_in[2];
  const float* W_i2h    = (const float*)d_in[3];
  const float* W_h2h    = (const float*)d_in[4];
  const float* b_h2h    = (const float*)d_in[5];
  const float* w_score  = (const float*)d_in[6];
  const float* W_ih     = (const float*)d_in[7];
  const float* W_hh     = (const float*)d_in[8];
  const float* b_ih     = (const float*)d_in[9];
  const float* b_hh     = (const float*)d_in[10];
  const float* Wf1      = (const float*)d_in[11];
  const float* bf1      = (const float*)d_in[12];
  const float* Wf2      = (const float*)d_in[13];
  const float* bf2      = (const float*)d_in[14];
  const float* Wz       = (const float*)d_in[15];
  const float* bz       = (const float*)d_in[16];
  const float* W_gen    = (const float*)d_in[17];
  const float* b_gen    = (const float*)d_in[18];
  const float* emb_tab  = (const float*)d_in[19];

  float* out = (float*)d_out;
  float* out_probs = out;                       // [B,NS,NCLS]
  float* out_attn  = out + 1291264;             // [B,T,NS]
  float* out_hid   = out + 2143232;             // [B,NS,H]
  float* out_char  = out + 8958976;             // [B,NS,H]

  char* wsp = (char*)d_ws;
  auto alloc = [&](size_t bytes) { char* p = wsp; wsp += (bytes + 255) & ~(size_t)255; return p; };
  unsigned short* bH    = (unsigned short*)alloc(33554432);  // [B,T,C] bf16
  unsigned short* Hproj = (unsigned short*)alloc(33554432);  // [B,T,H] bf16
  unsigned short* ASb   = (unsigned short*)alloc(13631488);  // [B*NS,512] bf16 (prologue only)
  unsigned short* embb  = (unsigned short*)alloc(6815744);   // [B,NS,NEMB] bf16
  unsigned short* FZpre = (unsigned short*)alloc(27262976);  // [B*NS,1024] bf16
  unsigned short* WA    = (unsigned short*)alloc(2621440);   // [2560,512]
  unsigned short* Wfz   = (unsigned short*)alloc(1048576);   // [1024,512]  (Wf1 | Wz-left)
  unsigned short* Wfz2  = (unsigned short*)alloc(1048576);   // [1024,512]  (Wf2 | Wz-right)
  unsigned short* WihE  = (unsigned short*)alloc(3145728);   // [2048,768]
  unsigned short* Wgenb = (unsigned short*)alloc(131072);    // [128,512]
  unsigned short* Wi2hb = (unsigned short*)alloc(524288);    // [512,512]
  float* biasA          = (float*)alloc(10240);              // [2560]
  float* biasFZ         = (float*)alloc(4096);               // [1024]
  unsigned* bars        = (unsigned*)alloc(1024);            // 8 groups x 32 uints
  // ---- aliased into ASb (dead after FZpre GEMM) ----
  char* ab = (char*)ASb;
  float* hpgh           = (float*)(ab);                      // [512,2560] f32 (5242880)
  unsigned short* ctx   = (unsigned short*)(ab + 5242880);   // [B,512] bf16 (524288)
  unsigned short* Ichar = (unsigned short*)(ab + 5767168);   // [B,512] bf16 (524288)
  float* cbuf           = (float*)(ab + 6291456);            // [B,512] f32 (1048576)
  unsigned short* hbuf  = (unsigned short*)(ab + 7340032);   // 2x [B,512] bf16 (1048576)

  // -------- prologue --------
  cvt_f32_bf16_k<<<dim3(16384), dim3(256), 0, stream>>>(batch_H, bH, 16777216);
  cvt_f32_bf16_k<<<dim3(6656), dim3(256), 0, stream>>>(AS, ASb, 6815744);
  cvt_f32_bf16_k<<<dim3(256), dim3(256), 0, stream>>>(W_i2h, Wi2hb, 262144);
  cvt_f32_bf16_k<<<dim3(1536), dim3(256), 0, stream>>>(W_ih, WihE, 1572864);
  embed_k<<<dim3(13312), dim3(256), 0, stream>>>(emb_tab, text, embb);
  pack_WA_k<<<dim3(5120), dim3(256), 0, stream>>>(W_h2h, W_hh, WA);
  pack_wfz_k<<<dim3(2048), dim3(256), 0, stream>>>(Wf1, Wz, 0, Wfz);
  pack_wfz_k<<<dim3(2048), dim3(256), 0, stream>>>(Wf2, Wz, 512, Wfz2);
  pack_Wgen_k<<<dim3(256), dim3(256), 0, stream>>>(W_gen, Wgenb);
  pack_bias_k<<<dim3(14), dim3(256), 0, stream>>>(b_h2h, b_ih, b_hh, bf2, bz, biasA, biasFZ);

  // H_proj = batch_H @ W_i2h^T  (M=32768, N=512, K=512) -> bf16
  gemm_tiled_k<false><<<dim3(4, 256), dim3(256), 0, stream>>>(
      bH, Wi2hb, nullptr, nullptr, Hproj, 512, 512, 512);

  // FZpre = AS @ [Wf2 | Wz-right]^T + [bf2 | bz]  (M=13312, N=1024, K=512) -> bf16
  gemm_tiled_k<false><<<dim3(8, 104), dim3(256), 0, stream>>>(
      ASb, Wfz2, biasFZ, nullptr, FZpre, 512, 1024, 1024);

  // ASb region dead -> init aliased state buffers + barriers
  hipMemsetAsync(cbuf, 0, 1048576, stream);
  hipMemsetAsync(hbuf, 0, 1048576, stream);
  hipMemsetAsync(bars, 0, 1024, stream);

  // -------- persistent scan + probs (256 blocks x 1024 thr; 8 groups, custom barriers) --------
  CoopArgs ca;
  ca.Hproj = Hproj; ca.bH = bH; ca.WA = WA; ca.Wfz = Wfz; ca.FZpre = FZpre;
  ca.WihE = WihE; ca.embb = embb; ca.Wgenb = Wgenb;
  ca.biasA = biasA; ca.w_score = w_score; ca.bf1 = bf1; ca.b_gen = b_gen;
  ca.hpgh = hpgh; ca.out_attn = out_attn; ca.out_char = out_char;
  ca.out_hid = out_hid; ca.out_probs = out_probs; ca.cbuf = cbuf;
  ca.ctx = ctx; ca.Ichar = Ichar; ca.hbuf = hbuf; ca.bars = bars;
  void* kargs[] = { (void*)&ca };
  hipLaunchCooperativeKernel((const void*)scan_coop_k, dim3(256), dim3(1024), kargs, 0, stream);
}

// Round 9
// 3043.457 us; speedup vs baseline: 1.7795x; 1.1785x over previous
//
#include <hip/hip_runtime.h>

#define NS_ 26
#define NCLS_ 97

typedef short bf16x8 __attribute__((ext_vector_type(8)));
typedef float f32x4 __attribute__((ext_vector_type(4)));

__device__ __forceinline__ unsigned short f2bf(float f) {
  union { float f; unsigned u; } v; v.f = f;
  unsigned r = v.u + 0x7fffu + ((v.u >> 16) & 1u);
  return (unsigned short)(r >> 16);
}
__device__ __forceinline__ float bf2f(unsigned short h) {
  union { unsigned u; float f; } v; v.u = ((unsigned)h) << 16;
  return v.f;
}
__device__ __forceinline__ float sigm_f(float x) { return 1.f / (1.f + __expf(-x)); }
__device__ __forceinline__ float tanh_f(float x) { return 1.f - 2.f / (1.f + __expf(2.f * x)); }

__device__ __forceinline__ void gl_lds16(const void* g, void* l) {
  __builtin_amdgcn_global_load_lds(
      (const __attribute__((address_space(1))) unsigned int*)g,
      (__attribute__((address_space(3))) unsigned int*)l, 16, 0, 0);
}

// ---- agent-scope (cross-XCD coherent, L2-bypassing) data movement ----
__device__ __forceinline__ float aload_f32(const float* p) {
  return __hip_atomic_load(p, __ATOMIC_RELAXED, __HIP_MEMORY_SCOPE_AGENT);
}
__device__ __forceinline__ void astore_f32(float* p, float v) {
  __hip_atomic_store(p, v, __ATOMIC_RELAXED, __HIP_MEMORY_SCOPE_AGENT);
}
__device__ __forceinline__ void astore_u32(unsigned* p, unsigned v) {
  __hip_atomic_store(p, v, __ATOMIC_RELAXED, __HIP_MEMORY_SCOPE_AGENT);
}
__device__ __forceinline__ void astore_u16(unsigned short* p, unsigned short v) {
  __hip_atomic_store(p, v, __ATOMIC_RELAXED, __HIP_MEMORY_SCOPE_AGENT);
}
__device__ __forceinline__ bf16x8 aload_b16x8(const unsigned short* p) {
  union { unsigned long long q[2]; bf16x8 v; } u;
  u.q[0] = __hip_atomic_load((const unsigned long long*)p, __ATOMIC_RELAXED, __HIP_MEMORY_SCOPE_AGENT);
  u.q[1] = __hip_atomic_load((const unsigned long long*)(p + 4), __ATOMIC_RELAXED, __HIP_MEMORY_SCOPE_AGENT);
  return u.v;
}

// light group barrier: no fences — comm data goes through agent-scope atomics,
// __syncthreads drains vmcnt before arrival.
__device__ __forceinline__ void gbar_light(unsigned* bar, unsigned* gen, unsigned target) {
  __syncthreads();
  if (threadIdx.x == 0) {
    const unsigned prev = __hip_atomic_fetch_add(bar, 1u, __ATOMIC_RELAXED, __HIP_MEMORY_SCOPE_AGENT);
    if (prev + 1u == target * 32u) {
      __hip_atomic_store(gen, target, __ATOMIC_RELAXED, __HIP_MEMORY_SCOPE_AGENT);
    } else {
      while (__hip_atomic_load(gen, __ATOMIC_RELAXED, __HIP_MEMORY_SCOPE_AGENT) < target) {}
    }
  }
  __syncthreads();
}

// heavy barrier: publishes normally-cached writes (L2 wb + inv) — used once before P5.
__device__ __forceinline__ void gbar_heavy(unsigned* bar, unsigned* gen, unsigned target) {
  __syncthreads();
  if (threadIdx.x == 0) {
    __threadfence();
    const unsigned prev = __hip_atomic_fetch_add(bar, 1u, __ATOMIC_RELAXED, __HIP_MEMORY_SCOPE_AGENT);
    if (prev + 1u == target * 32u) {
      __hip_atomic_store(gen, target, __ATOMIC_RELEASE, __HIP_MEMORY_SCOPE_AGENT);
    } else {
      while (__hip_atomic_load(gen, __ATOMIC_RELAXED, __HIP_MEMORY_SCOPE_AGENT) < target) {}
    }
    __threadfence();
  }
  __syncthreads();
}

// ============ tiled 128x128 GEMM (prologue) ============
template <bool OUTF>
__global__ __launch_bounds__(256) void gemm_tiled_k(
    const unsigned short* __restrict__ Ag, const unsigned short* __restrict__ Bg,
    const float* __restrict__ bias, float* __restrict__ outF,
    unsigned short* __restrict__ outB, int K, long ldo, int Nvalid) {
  __shared__ unsigned short As[128 * 64];
  __shared__ unsigned short Bs[128 * 64];
  const int tid = threadIdx.x;
  const int w = tid >> 6, l = tid & 63;
  const int l15 = l & 15, lq = l >> 4;
  const int wm = w >> 1, wn = w & 1;
  const long rowBase = (long)blockIdx.y * 128;
  const long colBase = (long)blockIdx.x * 128;
  const int lrow = l >> 3, ps_st = l & 7;
  f32x4 acc[4][4] = {};
  for (int kt = 0; kt < K; kt += 64) {
#pragma unroll
    for (int i = 0; i < 4; ++i) {
      const int row = i * 32 + w * 8 + lrow;
      const int ls = ps_st ^ (row & 7);
      gl_lds16(Ag + (rowBase + row) * K + kt + ls * 8, As + i * 2048 + w * 512);
      gl_lds16(Bg + (colBase + row) * K + kt + ls * 8, Bs + i * 2048 + w * 512);
    }
    __syncthreads();
#pragma unroll
    for (int kh = 0; kh < 2; ++kh) {
      bf16x8 af[4], bfr[4];
#pragma unroll
      for (int mi = 0; mi < 4; ++mi) {
        const int row = wm * 64 + mi * 16 + l15;
        const int ps = (kh * 4 + lq) ^ (row & 7);
        af[mi] = *(const bf16x8*)(As + row * 64 + ps * 8);
      }
#pragma unroll
      for (int ni = 0; ni < 4; ++ni) {
        const int row = wn * 64 + ni * 16 + l15;
        const int ps = (kh * 4 + lq) ^ (row & 7);
        bfr[ni] = *(const bf16x8*)(Bs + row * 64 + ps * 8);
      }
#pragma unroll
      for (int mi = 0; mi < 4; ++mi)
#pragma unroll
        for (int ni = 0; ni < 4; ++ni)
          acc[mi][ni] = __builtin_amdgcn_mfma_f32_16x16x32_bf16(af[mi], bfr[ni], acc[mi][ni], 0, 0, 0);
    }
    __syncthreads();
  }
#pragma unroll
  for (int mi = 0; mi < 4; ++mi)
#pragma unroll
    for (int ni = 0; ni < 4; ++ni) {
      const long gcol = colBase + wn * 64 + ni * 16 + l15;
      if (gcol >= Nvalid) continue;
      const float bv = bias ? bias[gcol] : 0.f;
#pragma unroll
      for (int r = 0; r < 4; ++r) {
        const long grow = rowBase + wm * 64 + mi * 16 + lq * 4 + r;
        const float v = acc[mi][ni][r] + bv;
        if (OUTF) outF[grow * ldo + gcol] = v;
        else      outB[grow * ldo + gcol] = f2bf(v);
      }
    }
}

// ============ persistent scan kernel: 256 blocks x 1024 thr, 8 groups x 32 blocks ============
struct CoopArgs {
  const unsigned short* Hproj;   // [B,64,512] bf16
  const unsigned short* bH;      // [B,64,512] bf16
  const unsigned short* WA;      // [2560,512] bf16
  const unsigned short* Wfz;     // [1024,512] bf16 (Wf1 | Wz-left)
  const unsigned short* FZpre;   // [B*NS,1024] bf16
  const unsigned short* WihE;    // [2048,768] bf16
  const unsigned short* embb;    // [B,NS,256] bf16
  const unsigned short* Wgenb;   // [128,512] bf16
  const float* biasA;            // [2560]
  const float* w_score;          // [512]
  const float* bf1;              // [512]
  const float* b_gen;            // [97]
  float* hpgh;                   // [512,2560]  (agent-atomic)
  float* out_attn;               // [B,64,NS]
  float* out_char;               // [B,NS,512]
  float* out_hid;                // [B,NS,512]
  float* out_probs;              // [B*NS,97]
  float* cbuf;                   // [B,512]     (block-private)
  unsigned short* ctx;           // [B,512] bf16 (agent-atomic)
  unsigned short* Ichar;         // [B,512] bf16 (agent-atomic)
  unsigned short* hbuf;          // 2x [B,512] bf16 (agent-atomic)
  unsigned* bars;                // 8 groups x 32 uints (bar, gen)
};

__global__ __launch_bounds__(1024, 4) void scan_coop_k(CoopArgs A) {
  __shared__ float smem[4872];   // [0..4352) phase scratch; [4352..4872) ws_t (stride 65)
  float* ws_t = smem + 4352;
  const int tid = threadIdx.x;
  const int sb = tid >> 8;           // sub-block 0..3
  const int stid = tid & 255;
  const int sw = stid >> 6;          // wave in sub-block 0..3
  const int l = tid & 63, l15 = l & 15, lq = l >> 4;
  const int bx = blockIdx.x;
  const int g = bx & 7;              // group (XCD round-robin heuristic)
  const int lb = bx >> 3;            // local block 0..31
  unsigned* bar = A.bars + g * 32;
  unsigned* gen = bar + 1;
  unsigned tgt = 0;
  const int u4 = lb * 4 + sb;        // sub-block slot 0..127 within group
  const long rb = (long)g * 64;      // group row base

  if (tid < 512) ws_t[(tid & 7) * 65 + (tid >> 3)] = A.w_score[tid];
  __syncthreads();

  for (int s = 0; s < NS_; ++s) {
    const unsigned short* hrd = A.hbuf + (s & 1) * 262144;
    unsigned short* hwr = A.hbuf + ((s + 1) & 1) * 262144;

    // ---- P1: hpgh[rb..rb+64, :2560] = h @ WA^T + biasA  (80 units of 64r x 32c) ----
    if (u4 < 80) {
      const int nbase = u4 * 32;
      const long mrow = rb + sw * 16 + l15;
      f32x4 acc[2] = {};
      for (int kt = 0; kt < 512; kt += 64) {
        const int k0 = kt + lq * 8, k1 = k0 + 32;
        const bf16x8 a0 = aload_b16x8(hrd + mrow * 512 + k0);
        const bf16x8 a1 = aload_b16x8(hrd + mrow * 512 + k1);
        bf16x8 b0[2], b1[2];
#pragma unroll
        for (int ni = 0; ni < 2; ++ni) {
          const long wr = nbase + ni * 16 + l15;
          b0[ni] = *(const bf16x8*)(A.WA + wr * 512 + k0);
          b1[ni] = *(const bf16x8*)(A.WA + wr * 512 + k1);
        }
#pragma unroll
        for (int ni = 0; ni < 2; ++ni) {
          acc[ni] = __builtin_amdgcn_mfma_f32_16x16x32_bf16(a0, b0[ni], acc[ni], 0, 0, 0);
          acc[ni] = __builtin_amdgcn_mfma_f32_16x16x32_bf16(a1, b1[ni], acc[ni], 0, 0, 0);
        }
      }
#pragma unroll
      for (int ni = 0; ni < 2; ++ni) {
        const int colg = nbase + ni * 16 + l15;
        const float bv = A.biasA[colg];
#pragma unroll
        for (int r = 0; r < 4; ++r) {
          const long rowg = rb + sw * 16 + lq * 4 + r;
          astore_f32(&A.hpgh[rowg * 2560 + colg], acc[ni][r] + bv);
        }
      }
    }
    gbar_light(bar, gen, ++tgt);

    // ---- P2: attention — 2 rows per block (512-thr row-teams) ----
    {
      const int ssb = tid >> 9;          // row-team 0/1
      const int sstid = tid & 511;
      const long b = rb + lb * 2 + ssb;
      float* S = smem + ssb * 1100;      // hp_t[520] | e[64] | csum[512]
      S[(sstid & 7) * 65 + (sstid >> 3)] = aload_f32(&A.hpgh[b * 2560 + sstid]);
      __syncthreads();
      const int w8 = sstid >> 6;
      float* e_s = S + 520;
#pragma unroll
      for (int tt = 0; tt < 8; ++tt) {
        const int t = w8 * 8 + tt;
        const bf16x8 hv = *(const bf16x8*)(A.Hproj + (b * 64 + t) * 512 + l * 8);
        float acc = 0.f;
#pragma unroll
        for (int j = 0; j < 8; ++j)
          acc += tanh_f(bf2f((unsigned short)hv[j]) + S[j * 65 + l]) * ws_t[j * 65 + l];
        acc += __shfl_xor(acc, 1);
        acc += __shfl_xor(acc, 2);
        acc += __shfl_xor(acc, 4);
        acc += __shfl_xor(acc, 8);
        acc += __shfl_xor(acc, 16);
        acc += __shfl_xor(acc, 32);
        if (l == 0) e_s[t] = acc;
      }
      __syncthreads();
      if (sstid < 64) {
        const float e = e_s[sstid];
        float m = e;
        for (int off = 32; off; off >>= 1) m = fmaxf(m, __shfl_xor(m, off));
        const float p = __expf(e - m);
        float sum = p;
        for (int off = 32; off; off >>= 1) sum += __shfl_xor(sum, off);
        const float al = p / sum;
        e_s[sstid] = al;
        A.out_attn[(b * 64 + sstid) * NS_ + s] = al;
      }
      __syncthreads();
      const int half = sstid >> 8, jj = sstid & 255;
      float c0 = 0.f, c1 = 0.f;
      const unsigned* bhp = (const unsigned*)(A.bH + (b * 64 + half * 32) * 512) + jj;
#pragma unroll 8
      for (int t = 0; t < 32; ++t) {
        const float al = e_s[half * 32 + t];
        const unsigned pv = bhp[(long)t * 256];
        c0 += al * bf2f((unsigned short)(pv & 0xffffu));
        c1 += al * bf2f((unsigned short)(pv >> 16));
      }
      float* csum = S + 584;
      if (half) { csum[jj * 2] = c0; csum[jj * 2 + 1] = c1; }
      __syncthreads();
      if (!half) {
        c0 += csum[jj * 2];
        c1 += csum[jj * 2 + 1];
        astore_u32((unsigned*)A.ctx + b * 256 + jj,
                   (unsigned)f2bf(c0) | ((unsigned)f2bf(c1) << 16));
      }
    }
    gbar_light(bar, gen, ++tgt);

    // ---- P3: gated fusion (64 units of 16r x 32c; wave=(which,colhalf)) ----
    {
      const bool act = u4 < 64;
      int j0 = 0;
      long b0 = rb;
      if (act) {
        j0 = (u4 & 15) * 32;
        b0 = rb + (u4 >> 4) * 16;
        const int which = sw >> 1, nh = sw & 1;
        f32x4 acc = {};
        const long arow = b0 + l15;
        const long gw = (long)(which ? 512 : 0) + j0 + nh * 16 + l15;
        for (int kt = 0; kt < 512; kt += 64) {
          const int k0 = kt + lq * 8, k1 = k0 + 32;
          const bf16x8 a0 = aload_b16x8(A.ctx + arow * 512 + k0);
          const bf16x8 a1 = aload_b16x8(A.ctx + arow * 512 + k1);
          const bf16x8 w0 = *(const bf16x8*)(A.Wfz + gw * 512 + k0);
          const bf16x8 w1 = *(const bf16x8*)(A.Wfz + gw * 512 + k1);
          acc = __builtin_amdgcn_mfma_f32_16x16x32_bf16(a0, w0, acc, 0, 0, 0);
          acc = __builtin_amdgcn_mfma_f32_16x16x32_bf16(a1, w1, acc, 0, 0, 0);
        }
        float* S = smem + sb * 1088;
#pragma unroll
        for (int r = 0; r < 4; ++r)
          S[which * 528 + (lq * 4 + r) * 33 + nh * 16 + l15] = acc[r];
      }
      __syncthreads();
      if (act) {
        const float* S = smem + sb * 1088;
#pragma unroll
        for (int i = 0; i < 2; ++i) {
          const int e = stid + i * 256;
          const int r = e >> 5, c = e & 31;
          const long b = b0 + r;
          const int j = j0 + c;
          const float f1 = tanh_f(S[r * 33 + c] + A.bf1[j]);
          const float zc = S[528 + r * 33 + c];
          const long pr = (b * NS_ + s) * 1024;
          const float f2 = tanh_f(bf2f(A.FZpre[pr + j]));
          const float z = sigm_f(zc + bf2f(A.FZpre[pr + 512 + j]));
          const float I = z * f1 + (1.f - z) * f2;
          A.out_char[(b * NS_ + s) * 512 + j] = I;
          astore_u16(A.Ichar + b * 512 + j, f2bf(I));
        }
      }
    }
    gbar_light(bar, gen, ++tgt);

    // ---- P4: gates GEMM + LSTM (128 units of 16r x 16c; wave = gate) ----
    {
      const int j0 = (u4 & 31) * 16;
      const long b0 = rb + (u4 >> 5) * 16;
      const int gg4 = sw;
      f32x4 acc = {};
      const long arow = b0 + l15;
      const long wrow = (long)gg4 * 512 + j0 + l15;
      for (int kt = 0; kt < 768; kt += 64) {
        const int k0 = kt + lq * 8, k1 = k0 + 32;
        const bf16x8 a0 = (k0 < 512)
            ? aload_b16x8(A.Ichar + arow * 512 + k0)
            : *(const bf16x8*)(A.embb + (arow * NS_ + s) * 256 + (k0 - 512));
        const bf16x8 a1 = (k1 < 512)
            ? aload_b16x8(A.Ichar + arow * 512 + k1)
            : *(const bf16x8*)(A.embb + (arow * NS_ + s) * 256 + (k1 - 512));
        const bf16x8 w0 = *(const bf16x8*)(A.WihE + wrow * 768 + k0);
        const bf16x8 w1 = *(const bf16x8*)(A.WihE + wrow * 768 + k1);
        acc = __builtin_amdgcn_mfma_f32_16x16x32_bf16(a0, w0, acc, 0, 0, 0);
        acc = __builtin_amdgcn_mfma_f32_16x16x32_bf16(a1, w1, acc, 0, 0, 0);
      }
      float* S = smem + sb * 1088;
#pragma unroll
      for (int r = 0; r < 4; ++r)
        S[gg4 * 272 + (lq * 4 + r) * 17 + l15] = acc[r];
      __syncthreads();
      {
        const float* S2 = smem + sb * 1088;
        const int r = stid >> 4, c = stid & 15;
        const long b = b0 + r;
        const int j = j0 + c;
        const float* ggh = A.hpgh + b * 2560 + 512;
        const float ig = sigm_f(S2[r * 17 + c] + aload_f32(ggh + j));
        const float fg = sigm_f(S2[272 + r * 17 + c] + aload_f32(ggh + 512 + j));
        const float gv = tanh_f(S2[544 + r * 17 + c] + aload_f32(ggh + 1024 + j));
        const float og = sigm_f(S2[816 + r * 17 + c] + aload_f32(ggh + 1536 + j));
        const float cn = fg * A.cbuf[b * 512 + j] + ig * gv;
        A.cbuf[b * 512 + j] = cn;
        const float h = og * tanh_f(cn);
        A.out_hid[(b * NS_ + s) * 512 + j] = h;
        astore_u16(hwr + b * 512 + j, f2bf(h));
      }
    }
    gbar_light(bar, gen, ++tgt);
  }

  // heavy barrier: publish out_hid (normal cached writes) for P5 reads
  gbar_heavy(bar, gen, ++tgt);

  // ---- P5: probs for group rows (52 units of 64x64; rows g*1664..+1664) ----
  if (u4 < 52) {
    const int rt = u4 >> 1, jt = u4 & 1;
    const int nbase = jt * 64;
    const long mrow = (long)g * 1664 + rt * 64 + sw * 16 + l15;
    f32x4 acc[4] = {};
    for (int kt = 0; kt < 512; kt += 32) {
      const int k = kt + lq * 8;
      const float4 av0 = *(const float4*)(A.out_hid + mrow * 512 + k);
      const float4 av1 = *(const float4*)(A.out_hid + mrow * 512 + k + 4);
      bf16x8 a;
      a[0] = (short)f2bf(av0.x); a[1] = (short)f2bf(av0.y);
      a[2] = (short)f2bf(av0.z); a[3] = (short)f2bf(av0.w);
      a[4] = (short)f2bf(av1.x); a[5] = (short)f2bf(av1.y);
      a[6] = (short)f2bf(av1.z); a[7] = (short)f2bf(av1.w);
#pragma unroll
      for (int nb = 0; nb < 4; ++nb) {
        const bf16x8 b = *(const bf16x8*)(A.Wgenb + (long)(nbase + nb * 16 + l15) * 512 + k);
        acc[nb] = __builtin_amdgcn_mfma_f32_16x16x32_bf16(a, b, acc[nb], 0, 0, 0);
      }
    }
#pragma unroll
    for (int nb = 0; nb < 4; ++nb) {
      const int colg = nbase + nb * 16 + l15;
      if (colg >= NCLS_) continue;
      const float bv = A.b_gen[colg];
#pragma unroll
      for (int r = 0; r < 4; ++r) {
        const long rowg = (long)g * 1664 + rt * 64 + sw * 16 + lq * 4 + r;
        A.out_probs[rowg * NCLS_ + colg] = acc[nb][r] + bv;
      }
    }
  }
}

// ============ prologue helpers ============
__global__ void cvt_f32_bf16_k(const float* __restrict__ in, unsigned short* __restrict__ out, long n) {
  const long i = ((long)blockIdx.x * 256 + threadIdx.x) * 4;
  if (i + 4 <= n) {
    const float4 v = *(const float4*)(in + i);
    ushort4 o;
    o.x = f2bf(v.x); o.y = f2bf(v.y); o.z = f2bf(v.z); o.w = f2bf(v.w);
    *(ushort4*)(out + i) = o;
  }
}

__global__ void embed_k(const float* __restrict__ emb_table, const int* __restrict__ text,
                        unsigned short* __restrict__ out) {
  const int bs = blockIdx.x, j = threadIdx.x;
  const int t = text[bs];
  out[(long)bs * 256 + j] = f2bf(emb_table[(long)t * 256 + j]);
}

__global__ void pack_WA_k(const float* __restrict__ W_h2h, const float* __restrict__ W_hh,
                          unsigned short* __restrict__ out) {
  const long idx = (long)blockIdx.x * 256 + threadIdx.x;
  const int row = (int)(idx >> 9), k = (int)(idx & 511);
  const float v = (row < 512) ? W_h2h[(long)row * 512 + k] : W_hh[(long)(row - 512) * 512 + k];
  out[idx] = f2bf(v);
}

__global__ void pack_wfz_k(const float* __restrict__ Wf, const float* __restrict__ Wz, int zoff,
                           unsigned short* __restrict__ out) {
  const long idx = (long)blockIdx.x * 256 + threadIdx.x;
  const int row = (int)(idx >> 9), k = (int)(idx & 511);
  const float v = (row < 512) ? Wf[(long)row * 512 + k]
                              : Wz[(long)(row - 512) * 1024 + zoff + k];
  out[idx] = f2bf(v);
}

__global__ void pack_Wgen_k(const float* __restrict__ W_gen, unsigned short* __restrict__ out) {
  const long idx = (long)blockIdx.x * 256 + threadIdx.x;  // 128*512
  const int row = (int)(idx >> 9), k = (int)(idx & 511);
  out[idx] = (row < NCLS_) ? f2bf(W_gen[(long)row * 512 + k]) : (unsigned short)0;
}

__global__ void pack_bias_k(const float* __restrict__ b_h2h, const float* __restrict__ b_ih,
                            const float* __restrict__ b_hh, const float* __restrict__ bf2,
                            const float* __restrict__ bz,
                            float* __restrict__ biasA, float* __restrict__ biasFZ) {
  const int i = blockIdx.x * 256 + threadIdx.x;  // 3584
  if (i < 2560) {
    biasA[i] = (i < 512) ? b_h2h[i] : (b_ih[i - 512] + b_hh[i - 512]);
  } else {
    const int j = i - 2560;
    if (j < 1024) biasFZ[j] = (j < 512) ? bf2[j] : bz[j - 512];
  }
}

extern "C" void kernel_launch(void* const* d_in, const int* in_sizes, int n_in,
                              void* d_out, int out_size, void* d_ws, size_t ws_size,
                              hipStream_t stream) {
  (void)in_sizes; (void)n_in; (void)out_size; (void)ws_size;
  const float* batch_H  = (const float*)d_in[0];
  const float* AS       = (const float*)d_in[1];
  const int*   text     = (const int*)d_in[2];
  const float* W_i2h    = (const float*)d_in[3];
  const float* W_h2h    = (const float*)d_in[4];
  const float* b_h2h    = (const float*)d_in[5];
  const float* w_score  = (const float*)d_in[6];
  const float* W_ih     = (const float*)d_in[7];
  const float* W_hh     = (const float*)d_in[8];
  const float* b_ih     = (const float*)d_in[9];
  const float* b_hh     = (const float*)d_in[10];
  const float* Wf1      = (const float*)d_in[11];
  const float* bf1      = (const float*)d_in[12];
  const float* Wf2      = (const float*)d_in[13];
  const float* bf2      = (const float*)d_in[14];
  const float* Wz       = (const float*)d_in[15];
  const float* bz       = (const float*)d_in[16];
  const float* W_gen    = (const float*)d_in[17];
  const float* b_gen    = (const float*)d_in[18];
  const float* emb_tab  = (const float*)d_in[19];

  float* out = (float*)d_out;
  float* out_probs = out;                       // [B,NS,NCLS]
  float* out_attn  = out + 1291264;             // [B,T,NS]
  float* out_hid   = out + 2143232;             // [B,NS,H]
  float* out_char  = out + 8958976;             // [B,NS,H]

  char* wsp = (char*)d_ws;
  auto alloc = [&](size_t bytes) { char* p = wsp; wsp += (bytes + 255) & ~(size_t)255; return p; };
  unsigned short* bH    = (unsigned short*)alloc(33554432);  // [B,T,C] bf16
  unsigned short* Hproj = (unsigned short*)alloc(33554432);  // [B,T,H] bf16
  unsigned short* ASb   = (unsigned short*)alloc(13631488);  // [B*NS,512] bf16 (prologue only)
  unsigned short* embb  = (unsigned short*)alloc(6815744);   // [B,NS,NEMB] bf16
  unsigned short* FZpre = (unsigned short*)alloc(27262976);  // [B*NS,1024] bf16
  unsigned short* WA    = (unsigned short*)alloc(2621440);   // [2560,512]
  unsigned short* Wfz   = (unsigned short*)alloc(1048576);   // [1024,512]  (Wf1 | Wz-left)
  unsigned short* Wfz2  = (unsigned short*)alloc(1048576);   // [1024,512]  (Wf2 | Wz-right)
  unsigned short* WihE  = (unsigned short*)alloc(3145728);   // [2048,768]
  unsigned short* Wgenb = (unsigned short*)alloc(131072);    // [128,512]
  unsigned short* Wi2hb = (unsigned short*)alloc(524288);    // [512,512]
  float* biasA          = (float*)alloc(10240);              // [2560]
  float* biasFZ         = (float*)alloc(4096);               // [1024]
  unsigned* bars        = (unsigned*)alloc(1024);            // 8 groups x 32 uints
  // ---- aliased into ASb (dead after FZpre GEMM) ----
  char* ab = (char*)ASb;
  float* hpgh           = (float*)(ab);                      // [512,2560] f32 (5242880)
  unsigned short* ctx   = (unsigned short*)(ab + 5242880);   // [B,512] bf16 (524288)
  unsigned short* Ichar = (unsigned short*)(ab + 5767168);   // [B,512] bf16 (524288)
  float* cbuf           = (float*)(ab + 6291456);            // [B,512] f32 (1048576)
  unsigned short* hbuf  = (unsigned short*)(ab + 7340032);   // 2x [B,512] bf16 (1048576)

  // -------- prologue --------
  cvt_f32_bf16_k<<<dim3(16384), dim3(256), 0, stream>>>(batch_H, bH, 16777216);
  cvt_f32_bf16_k<<<dim3(6656), dim3(256), 0, stream>>>(AS, ASb, 6815744);
  cvt_f32_bf16_k<<<dim3(256), dim3(256), 0, stream>>>(W_i2h, Wi2hb, 262144);
  cvt_f32_bf16_k<<<dim3(1536), dim3(256), 0, stream>>>(W_ih, WihE, 1572864);
  embed_k<<<dim3(13312), dim3(256), 0, stream>>>(emb_tab, text, embb);
  pack_WA_k<<<dim3(5120), dim3(256), 0, stream>>>(W_h2h, W_hh, WA);
  pack_wfz_k<<<dim3(2048), dim3(256), 0, stream>>>(Wf1, Wz, 0, Wfz);
  pack_wfz_k<<<dim3(2048), dim3(256), 0, stream>>>(Wf2, Wz, 512, Wfz2);
  pack_Wgen_k<<<dim3(256), dim3(256), 0, stream>>>(W_gen, Wgenb);
  pack_bias_k<<<dim3(14), dim3(256), 0, stream>>>(b_h2h, b_ih, b_hh, bf2, bz, biasA, biasFZ);

  // H_proj = batch_H @ W_i2h^T  (M=32768, N=512, K=512) -> bf16
  gemm_tiled_k<false><<<dim3(4, 256), dim3(256), 0, stream>>>(
      bH, Wi2hb, nullptr, nullptr, Hproj, 512, 512, 512);

  // FZpre = AS @ [Wf2 | Wz-right]^T + [bf2 | bz]  (M=13312, N=1024, K=512) -> bf16
  gemm_tiled_k<false><<<dim3(8, 104), dim3(256), 0, stream>>>(
      ASb, Wfz2, biasFZ, nullptr, FZpre, 512, 1024, 1024);

  // ASb region dead -> init aliased state buffers + barriers
  hipMemsetAsync(cbuf, 0, 1048576, stream);
  hipMemsetAsync(hbuf, 0, 1048576, stream);
  hipMemsetAsync(bars, 0, 1024, stream);

  // -------- persistent scan + probs (256 blocks x 1024 thr; 8 groups, light barriers) --------
  CoopArgs ca;
  ca.Hproj = Hproj; ca.bH = bH; ca.WA = WA; ca.Wfz = Wfz; ca.FZpre = FZpre;
  ca.WihE = WihE; ca.embb = embb; ca.Wgenb = Wgenb;
  ca.biasA = biasA; ca.w_score = w_score; ca.bf1 = bf1; ca.b_gen = b_gen;
  ca.hpgh = hpgh; ca.out_attn = out_attn; ca.out_char = out_char;
  ca.out_hid = out_hid; ca.out_probs = out_probs; ca.cbuf = cbuf;
  ca.ctx = ctx; ca.Ichar = Ichar; ca.hbuf = hbuf; ca.bars = bars;
  void* kargs[] = { (void*)&ca };
  hipLaunchCooperativeKernel((const void*)scan_coop_k, dim3(256), dim3(1024), kargs, 0, stream);
}

// Round 10
// 2658.686 us; speedup vs baseline: 2.0370x; 1.1447x over previous
//
#include <hip/hip_runtime.h>

#define NS_ 26
#define NCLS_ 97

typedef short bf16x8 __attribute__((ext_vector_type(8)));
typedef float f32x4 __attribute__((ext_vector_type(4)));

__device__ __forceinline__ unsigned short f2bf(float f) {
  union { float f; unsigned u; } v; v.f = f;
  unsigned r = v.u + 0x7fffu + ((v.u >> 16) & 1u);
  return (unsigned short)(r >> 16);
}
__device__ __forceinline__ float bf2f(unsigned short h) {
  union { unsigned u; float f; } v; v.u = ((unsigned)h) << 16;
  return v.f;
}
__device__ __forceinline__ float sigm_f(float x) { return 1.f / (1.f + __expf(-x)); }
__device__ __forceinline__ float tanh_f(float x) { return 1.f - 2.f / (1.f + __expf(2.f * x)); }

__device__ __forceinline__ void gl_lds16(const void* g, void* l) {
  __builtin_amdgcn_global_load_lds(
      (const __attribute__((address_space(1))) unsigned int*)g,
      (__attribute__((address_space(3))) unsigned int*)l, 16, 0, 0);
}

// ============ tiled 128x128 GEMM (prologue) ============
template <bool OUTF>
__global__ __launch_bounds__(256) void gemm_tiled_k(
    const unsigned short* __restrict__ Ag, const unsigned short* __restrict__ Bg,
    const float* __restrict__ bias, float* __restrict__ outF,
    unsigned short* __restrict__ outB, int K, long ldo, int Nvalid) {
  __shared__ unsigned short As[128 * 64];
  __shared__ unsigned short Bs[128 * 64];
  const int tid = threadIdx.x;
  const int w = tid >> 6, l = tid & 63;
  const int l15 = l & 15, lq = l >> 4;
  const int wm = w >> 1, wn = w & 1;
  const long rowBase = (long)blockIdx.y * 128;
  const long colBase = (long)blockIdx.x * 128;
  const int lrow = l >> 3, ps_st = l & 7;
  f32x4 acc[4][4] = {};
  for (int kt = 0; kt < K; kt += 64) {
#pragma unroll
    for (int i = 0; i < 4; ++i) {
      const int row = i * 32 + w * 8 + lrow;
      const int ls = ps_st ^ (row & 7);
      gl_lds16(Ag + (rowBase + row) * K + kt + ls * 8, As + i * 2048 + w * 512);
      gl_lds16(Bg + (colBase + row) * K + kt + ls * 8, Bs + i * 2048 + w * 512);
    }
    __syncthreads();
#pragma unroll
    for (int kh = 0; kh < 2; ++kh) {
      bf16x8 af[4], bfr[4];
#pragma unroll
      for (int mi = 0; mi < 4; ++mi) {
        const int row = wm * 64 + mi * 16 + l15;
        const int ps = (kh * 4 + lq) ^ (row & 7);
        af[mi] = *(const bf16x8*)(As + row * 64 + ps * 8);
      }
#pragma unroll
      for (int ni = 0; ni < 4; ++ni) {
        const int row = wn * 64 + ni * 16 + l15;
        const int ps = (kh * 4 + lq) ^ (row & 7);
        bfr[ni] = *(const bf16x8*)(Bs + row * 64 + ps * 8);
      }
#pragma unroll
      for (int mi = 0; mi < 4; ++mi)
#pragma unroll
        for (int ni = 0; ni < 4; ++ni)
          acc[mi][ni] = __builtin_amdgcn_mfma_f32_16x16x32_bf16(af[mi], bfr[ni], acc[mi][ni], 0, 0, 0);
    }
    __syncthreads();
  }
#pragma unroll
  for (int mi = 0; mi < 4; ++mi)
#pragma unroll
    for (int ni = 0; ni < 4; ++ni) {
      const long gcol = colBase + wn * 64 + ni * 16 + l15;
      if (gcol >= Nvalid) continue;
      const float bv = bias ? bias[gcol] : 0.f;
#pragma unroll
      for (int r = 0; r < 4; ++r) {
        const long grow = rowBase + wm * 64 + mi * 16 + lq * 4 + r;
        const float v = acc[mi][ni][r] + bv;
        if (OUTF) outF[grow * ldo + gcol] = v;
        else      outB[grow * ldo + gcol] = f2bf(v);
      }
    }
}

// ============ K1: fused hp-GEMV + attention (1 block per batch row) ============
// Wt4 layout: Wt4[(k>>2)*2048 + j*4 + (k&3)] = W_h2h[j][k]
__global__ __launch_bounds__(512) void attn_fused_k(
    const unsigned short* __restrict__ hrd, const unsigned short* __restrict__ Wt4,
    const float* __restrict__ b_h2h, const unsigned short* __restrict__ Hproj,
    const unsigned short* __restrict__ bH, const float* __restrict__ w_score,
    float* __restrict__ attn_map, unsigned short* __restrict__ ctx, int s) {
  const int b = blockIdx.x, tid = threadIdx.x;
  __shared__ float hs[512];
  __shared__ float hp_t[520];
  __shared__ float ws_t[520];
  __shared__ float e_s[64];
  __shared__ float csum[512];
  hs[tid] = bf2f(hrd[(long)b * 512 + tid]);
  ws_t[(tid & 7) * 65 + (tid >> 3)] = w_score[tid];
  __syncthreads();
  // GEMV: hp[tid] = b_h2h[tid] + sum_k hs[k] * W_h2h[tid][k]
  {
    float acc = b_h2h[tid];
    const unsigned short* wp = Wt4 + tid * 4;
#pragma unroll 4
    for (int k4 = 0; k4 < 128; ++k4) {
      const ushort4 wv = *(const ushort4*)(wp + k4 * 2048);
      const f32x4 hv = *(const f32x4*)(hs + k4 * 4);
      acc += bf2f(wv.x) * hv[0] + bf2f(wv.y) * hv[1]
           + bf2f(wv.z) * hv[2] + bf2f(wv.w) * hv[3];
    }
    hp_t[(tid & 7) * 65 + (tid >> 3)] = acc;
  }
  __syncthreads();
  // score: wave w8 handles 8 t-rows; lane l covers h = l*8..+8
  const int w8 = tid >> 6, l = tid & 63;
#pragma unroll
  for (int tt = 0; tt < 8; ++tt) {
    const int t = w8 * 8 + tt;
    const bf16x8 hv = *(const bf16x8*)(Hproj + ((long)b * 64 + t) * 512 + l * 8);
    float acc = 0.f;
#pragma unroll
    for (int j = 0; j < 8; ++j)
      acc += tanh_f(bf2f((unsigned short)hv[j]) + hp_t[j * 65 + l]) * ws_t[j * 65 + l];
    acc += __shfl_xor(acc, 1);
    acc += __shfl_xor(acc, 2);
    acc += __shfl_xor(acc, 4);
    acc += __shfl_xor(acc, 8);
    acc += __shfl_xor(acc, 16);
    acc += __shfl_xor(acc, 32);
    if (l == 0) e_s[t] = acc;
  }
  __syncthreads();
  if (tid < 64) {
    const float e = e_s[tid];
    float m = e;
    for (int off = 32; off; off >>= 1) m = fmaxf(m, __shfl_xor(m, off));
    const float p = __expf(e - m);
    float sum = p;
    for (int off = 32; off; off >>= 1) sum += __shfl_xor(sum, off);
    const float a = p / sum;
    e_s[tid] = a;
    attn_map[((long)b * 64 + tid) * NS_ + s] = a;
  }
  __syncthreads();
  const int half = tid >> 8, jj = tid & 255;
  float c0 = 0.f, c1 = 0.f;
  const unsigned* bhp = (const unsigned*)(bH + ((long)b * 64 + half * 32) * 512) + jj;
#pragma unroll 8
  for (int t = 0; t < 32; ++t) {
    const float a = e_s[half * 32 + t];
    const unsigned pv = bhp[(long)t * 256];
    c0 += a * bf2f((unsigned short)(pv & 0xffffu));
    c1 += a * bf2f((unsigned short)(pv >> 16));
  }
  if (half) { csum[jj * 2] = c0; csum[jj * 2 + 1] = c1; }
  __syncthreads();
  if (!half) {
    c0 += csum[jj * 2];
    c1 += csum[jj * 2 + 1];
    ((unsigned*)ctx)[(long)b * 256 + jj] = (unsigned)f2bf(c0) | ((unsigned)f2bf(c1) << 16);
  }
}

// ============ K2: gated fused (round-3 proven) ============
__global__ __launch_bounds__(512) void gated_fused_k(
    const unsigned short* __restrict__ ctx, const unsigned short* __restrict__ Wfz,
    const unsigned short* __restrict__ FZpre, const float* __restrict__ bf1,
    unsigned short* __restrict__ Ichar, float* __restrict__ Char_out, int s) {
  __shared__ float ls[2 * 64 * 65];
  const int tid = threadIdx.x, w = tid >> 6, l = tid & 63, l15 = l & 15, lq = l >> 4;
  const int b0 = blockIdx.y * 64, j0 = blockIdx.x * 64;
  const int mi2 = w & 1, nq = w >> 1;
  f32x4 acc[2][2] = {};
  for (int kt = 0; kt < 512; kt += 64) {
    const int k0 = kt + lq * 8, k1 = k0 + 32;
    bf16x8 a0[2], a1[2], bb0[2], bb1[2];
#pragma unroll
    for (int mi = 0; mi < 2; ++mi) {
      const long row = b0 + mi2 * 32 + mi * 16 + l15;
      a0[mi] = *(const bf16x8*)(ctx + row * 512 + k0);
      a1[mi] = *(const bf16x8*)(ctx + row * 512 + k1);
    }
#pragma unroll
    for (int ni = 0; ni < 2; ++ni) {
      const int wl = nq * 32 + ni * 16 + l15;
      const long gw = (wl < 64) ? (j0 + wl) : (512 + j0 + wl - 64);
      bb0[ni] = *(const bf16x8*)(Wfz + gw * 512 + k0);
      bb1[ni] = *(const bf16x8*)(Wfz + gw * 512 + k1);
    }
#pragma unroll
    for (int mi = 0; mi < 2; ++mi)
#pragma unroll
      for (int ni = 0; ni < 2; ++ni) {
        acc[mi][ni] = __builtin_amdgcn_mfma_f32_16x16x32_bf16(a0[mi], bb0[ni], acc[mi][ni], 0, 0, 0);
        acc[mi][ni] = __builtin_amdgcn_mfma_f32_16x16x32_bf16(a1[mi], bb1[ni], acc[mi][ni], 0, 0, 0);
      }
  }
  float* dst = ls + (nq >> 1) * (64 * 65);
#pragma unroll
  for (int mi = 0; mi < 2; ++mi)
#pragma unroll
    for (int ni = 0; ni < 2; ++ni)
#pragma unroll
      for (int r = 0; r < 4; ++r) {
        const int rl = mi2 * 32 + mi * 16 + lq * 4 + r;
        const int cl = (nq & 1) * 32 + ni * 16 + l15;
        dst[rl * 65 + cl] = acc[mi][ni][r];
      }
  __syncthreads();
#pragma unroll
  for (int i = 0; i < 8; ++i) {
    const int e = tid + i * 512;
    const int r = e >> 6, c = e & 63;
    const long b = b0 + r;
    const int j = j0 + c;
    const float f1 = tanh_f(ls[r * 65 + c] + bf1[j]);
    const float zc = ls[64 * 65 + r * 65 + c];
    const long pr = (b * NS_ + s) * 1024;
    const float f2 = tanh_f(bf2f(FZpre[pr + j]));
    const float z = sigm_f(zc + bf2f(FZpre[pr + 512 + j]));
    const float I = z * f1 + (1.f - z) * f2;
    Char_out[(b * NS_ + s) * 512 + j] = I;
    Ichar[b * 512 + j] = f2bf(I);
  }
}

// ============ K3: gates GEMM K=1280 ([Ichar|emb|h] @ [W_ih|W_hh]^T) + LSTM ============
__global__ __launch_bounds__(512) void gates_lstm_k(
    const unsigned short* __restrict__ Ichar, const unsigned short* __restrict__ embb,
    const unsigned short* __restrict__ hrd, const unsigned short* __restrict__ Wihh,
    const float* __restrict__ biasG, float* __restrict__ cbuf,
    float* __restrict__ hid_out, unsigned short* __restrict__ hwr, int s) {
  __shared__ float gs[4 * 32 * 65];
  const int tid = threadIdx.x, w = tid >> 6, l = tid & 63, l15 = l & 15, lq = l >> 4;
  const int b0 = blockIdx.y * 32, j0 = blockIdx.x * 64;
  const int g = w & 3, mi = w >> 2;
  const long arow = b0 + mi * 16 + l15;
  f32x4 acc[4] = {};
  for (int kt = 0; kt < 1280; kt += 64) {
    const int k0 = kt + lq * 8, k1 = k0 + 32;
    bf16x8 a0, a1, b0r[4], b1r[4];
    if (kt < 512) {
      a0 = *(const bf16x8*)(Ichar + arow * 512 + k0);
      a1 = *(const bf16x8*)(Ichar + arow * 512 + k1);
    } else if (kt < 768) {
      a0 = *(const bf16x8*)(embb + (arow * NS_ + s) * 256 + (k0 - 512));
      a1 = *(const bf16x8*)(embb + (arow * NS_ + s) * 256 + (k1 - 512));
    } else {
      a0 = *(const bf16x8*)(hrd + arow * 512 + (k0 - 768));
      a1 = *(const bf16x8*)(hrd + arow * 512 + (k1 - 768));
    }
#pragma unroll
    for (int ni = 0; ni < 4; ++ni) {
      const long wrow = (long)g * 512 + j0 + ni * 16 + l15;
      b0r[ni] = *(const bf16x8*)(Wihh + wrow * 1280 + k0);
      b1r[ni] = *(const bf16x8*)(Wihh + wrow * 1280 + k1);
    }
#pragma unroll
    for (int ni = 0; ni < 4; ++ni) {
      acc[ni] = __builtin_amdgcn_mfma_f32_16x16x32_bf16(a0, b0r[ni], acc[ni], 0, 0, 0);
      acc[ni] = __builtin_amdgcn_mfma_f32_16x16x32_bf16(a1, b1r[ni], acc[ni], 0, 0, 0);
    }
  }
#pragma unroll
  for (int ni = 0; ni < 4; ++ni)
#pragma unroll
    for (int r = 0; r < 4; ++r) {
      const int rl = mi * 16 + lq * 4 + r;
      const int cl = ni * 16 + l15;
      gs[(g * 32 + rl) * 65 + cl] = acc[ni][r];
    }
  __syncthreads();
#pragma unroll
  for (int i = 0; i < 4; ++i) {
    const int e = tid + i * 512;
    const int r = e >> 6, c = e & 63;
    const long b = b0 + r;
    const int j = j0 + c;
    const float ig = sigm_f(gs[(0 * 32 + r) * 65 + c] + biasG[j]);
    const float fg = sigm_f(gs[(1 * 32 + r) * 65 + c] + biasG[512 + j]);
    const float gg = tanh_f(gs[(2 * 32 + r) * 65 + c] + biasG[1024 + j]);
    const float og = sigm_f(gs[(3 * 32 + r) * 65 + c] + biasG[1536 + j]);
    const float cn = fg * cbuf[b * 512 + j] + ig * gg;
    cbuf[b * 512 + j] = cn;
    const float h = og * tanh_f(cn);
    hid_out[(b * NS_ + s) * 512 + j] = h;
    hwr[b * 512 + j] = f2bf(h);
  }
}

// ============ final probs GEMM ============
__global__ __launch_bounds__(256) void probs_k(
    const float* __restrict__ Af, const unsigned short* __restrict__ Wg,
    const float* __restrict__ bias, float* __restrict__ outp) {
  const int tid = threadIdx.x, w = tid >> 6, l = tid & 63, l15 = l & 15, lq = l >> 4;
  const long mrow = (long)blockIdx.y * 64 + w * 16 + l15;
  const int nbase = blockIdx.x * 64;
  f32x4 acc[4] = {};
  for (int kt = 0; kt < 512; kt += 32) {
    const int k = kt + lq * 8;
    const float4 av0 = *(const float4*)(Af + mrow * 512 + k);
    const float4 av1 = *(const float4*)(Af + mrow * 512 + k + 4);
    bf16x8 a;
    a[0] = (short)f2bf(av0.x); a[1] = (short)f2bf(av0.y);
    a[2] = (short)f2bf(av0.z); a[3] = (short)f2bf(av0.w);
    a[4] = (short)f2bf(av1.x); a[5] = (short)f2bf(av1.y);
    a[6] = (short)f2bf(av1.z); a[7] = (short)f2bf(av1.w);
#pragma unroll
    for (int nb = 0; nb < 4; ++nb) {
      const bf16x8 b = *(const bf16x8*)(Wg + (long)(nbase + nb * 16 + l15) * 512 + k);
      acc[nb] = __builtin_amdgcn_mfma_f32_16x16x32_bf16(a, b, acc[nb], 0, 0, 0);
    }
  }
#pragma unroll
  for (int nb = 0; nb < 4; ++nb) {
    const int colg = nbase + nb * 16 + l15;
    if (colg >= NCLS_) continue;
    const float bv = bias[colg];
#pragma unroll
    for (int r = 0; r < 4; ++r) {
      const long rowg = (long)blockIdx.y * 64 + w * 16 + lq * 4 + r;
      outp[rowg * NCLS_ + colg] = acc[nb][r] + bv;
    }
  }
}

// ============ prologue helpers ============
__global__ void cvt_f32_bf16_k(const float* __restrict__ in, unsigned short* __restrict__ out, long n) {
  const long i = ((long)blockIdx.x * 256 + threadIdx.x) * 4;
  if (i + 4 <= n) {
    const float4 v = *(const float4*)(in + i);
    ushort4 o;
    o.x = f2bf(v.x); o.y = f2bf(v.y); o.z = f2bf(v.z); o.w = f2bf(v.w);
    *(ushort4*)(out + i) = o;
  }
}

__global__ void embed_k(const float* __restrict__ emb_table, const int* __restrict__ text,
                        unsigned short* __restrict__ out) {
  const int bs = blockIdx.x, j = threadIdx.x;
  const int t = text[bs];
  out[(long)bs * 256 + j] = f2bf(emb_table[(long)t * 256 + j]);
}

// Wt4[(k>>2)*2048 + j*4 + (k&3)] = W_h2h[j][k]
__global__ void pack_Wt4_k(const float* __restrict__ W, unsigned short* __restrict__ out) {
  const long idx = (long)blockIdx.x * 256 + threadIdx.x;  // 262144
  const int j = (int)(idx >> 9), k = (int)(idx & 511);
  out[((long)(k >> 2) * 2048) + j * 4 + (k & 3)] = f2bf(W[idx]);
}

// Wihh [2048,1280]: cols 0..767 = W_ih, cols 768..1279 = W_hh
__global__ void pack_Wihh_k(const float* __restrict__ W_ih, const float* __restrict__ W_hh,
                            unsigned short* __restrict__ out) {
  const long idx = (long)blockIdx.x * 256 + threadIdx.x;  // 2048*1280
  const int row = (int)(idx / 1280), c = (int)(idx % 1280);
  const float v = (c < 768) ? W_ih[(long)row * 768 + c] : W_hh[(long)row * 512 + (c - 768)];
  out[idx] = f2bf(v);
}

__global__ void pack_wfz_k(const float* __restrict__ Wf, const float* __restrict__ Wz, int zoff,
                           unsigned short* __restrict__ out) {
  const long idx = (long)blockIdx.x * 256 + threadIdx.x;
  const int row = (int)(idx >> 9), k = (int)(idx & 511);
  const float v = (row < 512) ? Wf[(long)row * 512 + k]
                              : Wz[(long)(row - 512) * 1024 + zoff + k];
  out[idx] = f2bf(v);
}

__global__ void pack_Wgen_k(const float* __restrict__ W_gen, unsigned short* __restrict__ out) {
  const long idx = (long)blockIdx.x * 256 + threadIdx.x;  // 128*512
  const int row = (int)(idx >> 9), k = (int)(idx & 511);
  out[idx] = (row < NCLS_) ? f2bf(W_gen[(long)row * 512 + k]) : (unsigned short)0;
}

// biasG [2048] = b_ih + b_hh ; biasFZ [1024] = [bf2 | bz]
__global__ void pack_bias_k(const float* __restrict__ b_ih, const float* __restrict__ b_hh,
                            const float* __restrict__ bf2, const float* __restrict__ bz,
                            float* __restrict__ biasG, float* __restrict__ biasFZ) {
  const int i = blockIdx.x * 256 + threadIdx.x;  // 3072
  if (i < 2048) {
    biasG[i] = b_ih[i] + b_hh[i];
  } else {
    const int j = i - 2048;
    biasFZ[j] = (j < 512) ? bf2[j] : bz[j - 512];
  }
}

extern "C" void kernel_launch(void* const* d_in, const int* in_sizes, int n_in,
                              void* d_out, int out_size, void* d_ws, size_t ws_size,
                              hipStream_t stream) {
  (void)in_sizes; (void)n_in; (void)out_size; (void)ws_size;
  const float* batch_H  = (const float*)d_in[0];
  const float* AS       = (const float*)d_in[1];
  const int*   text     = (const int*)d_in[2];
  const float* W_i2h    = (const float*)d_in[3];
  const float* W_h2h    = (const float*)d_in[4];
  const float* b_h2h    = (const float*)d_in[5];
  const float* w_score  = (const float*)d_in[6];
  const float* W_ih     = (const float*)d_in[7];
  const float* W_hh     = (const float*)d_in[8];
  const float* b_ih     = (const float*)d_in[9];
  const float* b_hh     = (const float*)d_in[10];
  const float* Wf1      = (const float*)d_in[11];
  const float* bf1      = (const float*)d_in[12];
  const float* Wf2      = (const float*)d_in[13];
  const float* bf2      = (const float*)d_in[14];
  const float* Wz       = (const float*)d_in[15];
  const float* bz       = (const float*)d_in[16];
  const float* W_gen    = (const float*)d_in[17];
  const float* b_gen    = (const float*)d_in[18];
  const float* emb_tab  = (const float*)d_in[19];

  float* out = (float*)d_out;
  float* out_probs = out;                       // [B,NS,NCLS]
  float* out_attn  = out + 1291264;             // [B,T,NS]
  float* out_hid   = out + 2143232;             // [B,NS,H]
  float* out_char  = out + 8958976;             // [B,NS,H]

  char* wsp = (char*)d_ws;
  auto alloc = [&](size_t bytes) { char* p = wsp; wsp += (bytes + 255) & ~(size_t)255; return p; };
  unsigned short* bH    = (unsigned short*)alloc(33554432);  // [B,T,C] bf16
  unsigned short* Hproj = (unsigned short*)alloc(33554432);  // [B,T,H] bf16
  unsigned short* ASb   = (unsigned short*)alloc(13631488);  // [B*NS,512] bf16 (prologue only)
  unsigned short* embb  = (unsigned short*)alloc(6815744);   // [B,NS,NEMB] bf16
  unsigned short* FZpre = (unsigned short*)alloc(27262976);  // [B*NS,1024] bf16
  unsigned short* Wt4   = (unsigned short*)alloc(524288);    // [128][512][4] packed W_h2h
  unsigned short* Wfz   = (unsigned short*)alloc(1048576);   // [1024,512]  (Wf1 | Wz-left)
  unsigned short* Wfz2  = (unsigned short*)alloc(1048576);   // [1024,512]  (Wf2 | Wz-right)
  unsigned short* Wihh  = (unsigned short*)alloc(5242880);   // [2048,1280]
  unsigned short* Wgenb = (unsigned short*)alloc(131072);    // [128,512]
  unsigned short* Wi2hb = (unsigned short*)alloc(524288);    // [512,512]
  float* biasG          = (float*)alloc(8192);               // [2048]
  float* biasFZ         = (float*)alloc(4096);               // [1024]
  // ---- aliased into ASb (dead after FZpre GEMM) ----
  char* ab = (char*)ASb;
  unsigned short* ctx   = (unsigned short*)(ab);             // [B,512] bf16 (524288)
  unsigned short* Ichar = (unsigned short*)(ab + 524288);    // [B,512] bf16 (524288)
  float* cbuf           = (float*)(ab + 1048576);            // [B,512] f32 (1048576)
  unsigned short* hbuf  = (unsigned short*)(ab + 2097152);   // 2x [B,512] bf16 (1048576)

  // -------- prologue --------
  cvt_f32_bf16_k<<<dim3(16384), dim3(256), 0, stream>>>(batch_H, bH, 16777216);
  cvt_f32_bf16_k<<<dim3(6656), dim3(256), 0, stream>>>(AS, ASb, 6815744);
  cvt_f32_bf16_k<<<dim3(256), dim3(256), 0, stream>>>(W_i2h, Wi2hb, 262144);
  embed_k<<<dim3(13312), dim3(256), 0, stream>>>(emb_tab, text, embb);
  pack_Wt4_k<<<dim3(1024), dim3(256), 0, stream>>>(W_h2h, Wt4);
  pack_Wihh_k<<<dim3(10240), dim3(256), 0, stream>>>(W_ih, W_hh, Wihh);
  pack_wfz_k<<<dim3(2048), dim3(256), 0, stream>>>(Wf1, Wz, 0, Wfz);
  pack_wfz_k<<<dim3(2048), dim3(256), 0, stream>>>(Wf2, Wz, 512, Wfz2);
  pack_Wgen_k<<<dim3(256), dim3(256), 0, stream>>>(W_gen, Wgenb);
  pack_bias_k<<<dim3(12), dim3(256), 0, stream>>>(b_ih, b_hh, bf2, bz, biasG, biasFZ);

  // H_proj = batch_H @ W_i2h^T  (M=32768, N=512, K=512) -> bf16
  gemm_tiled_k<false><<<dim3(4, 256), dim3(256), 0, stream>>>(
      bH, Wi2hb, nullptr, nullptr, Hproj, 512, 512, 512);

  // FZpre = AS @ [Wf2 | Wz-right]^T + [bf2 | bz]  (M=13312, N=1024, K=512) -> bf16
  gemm_tiled_k<false><<<dim3(8, 104), dim3(256), 0, stream>>>(
      ASb, Wfz2, biasFZ, nullptr, FZpre, 512, 1024, 1024);

  // ASb region dead -> init aliased state buffers
  hipMemsetAsync(cbuf, 0, 1048576, stream);
  hipMemsetAsync(hbuf, 0, 1048576, stream);

  // -------- 26-step scan: 3 kernels per step --------
  for (int s = 0; s < NS_; ++s) {
    unsigned short* hrd = hbuf + (s & 1) * 262144;
    unsigned short* hwr = hbuf + ((s + 1) & 1) * 262144;
    attn_fused_k<<<dim3(512), dim3(512), 0, stream>>>(
        hrd, Wt4, b_h2h, Hproj, bH, w_score, out_attn, ctx, s);
    gated_fused_k<<<dim3(8, 8), dim3(512), 0, stream>>>(
        ctx, Wfz, FZpre, bf1, Ichar, out_char, s);
    gates_lstm_k<<<dim3(8, 16), dim3(512), 0, stream>>>(
        Ichar, embb, hrd, Wihh, biasG, cbuf, out_hid, hwr, s);
  }

  // probs = out_hid @ W_gen^T + b_gen
  probs_k<<<dim3(2, 208), dim3(256), 0, stream>>>(out_hid, Wgenb, b_gen, out_probs);
}

// Round 11
// 1966.542 us; speedup vs baseline: 2.7540x; 1.3520x over previous
//
#include <hip/hip_runtime.h>

#define NS_ 26
#define NCLS_ 97

typedef short bf16x8 __attribute__((ext_vector_type(8)));
typedef float f32x4 __attribute__((ext_vector_type(4)));

__device__ __forceinline__ unsigned short f2bf(float f) {
  union { float f; unsigned u; } v; v.f = f;
  unsigned r = v.u + 0x7fffu + ((v.u >> 16) & 1u);
  return (unsigned short)(r >> 16);
}
__device__ __forceinline__ float bf2f(unsigned short h) {
  union { unsigned u; float f; } v; v.u = ((unsigned)h) << 16;
  return v.f;
}
__device__ __forceinline__ float sigm_f(float x) { return 1.f / (1.f + __expf(-x)); }
__device__ __forceinline__ float tanh_f(float x) { return 1.f - 2.f / (1.f + __expf(2.f * x)); }

__device__ __forceinline__ void gl_lds16(const void* g, void* l) {
  __builtin_amdgcn_global_load_lds(
      (const __attribute__((address_space(1))) unsigned int*)g,
      (__attribute__((address_space(3))) unsigned int*)l, 16, 0, 0);
}

// ============ tiled 128x128 GEMM (prologue) ============
template <bool OUTF>
__global__ __launch_bounds__(256) void gemm_tiled_k(
    const unsigned short* __restrict__ Ag, const unsigned short* __restrict__ Bg,
    const float* __restrict__ bias, float* __restrict__ outF,
    unsigned short* __restrict__ outB, int K, long ldo, int Nvalid) {
  __shared__ unsigned short As[128 * 64];
  __shared__ unsigned short Bs[128 * 64];
  const int tid = threadIdx.x;
  const int w = tid >> 6, l = tid & 63;
  const int l15 = l & 15, lq = l >> 4;
  const int wm = w >> 1, wn = w & 1;
  const long rowBase = (long)blockIdx.y * 128;
  const long colBase = (long)blockIdx.x * 128;
  const int lrow = l >> 3, ps_st = l & 7;
  f32x4 acc[4][4] = {};
  for (int kt = 0; kt < K; kt += 64) {
#pragma unroll
    for (int i = 0; i < 4; ++i) {
      const int row = i * 32 + w * 8 + lrow;
      const int ls = ps_st ^ (row & 7);
      gl_lds16(Ag + (rowBase + row) * K + kt + ls * 8, As + i * 2048 + w * 512);
      gl_lds16(Bg + (colBase + row) * K + kt + ls * 8, Bs + i * 2048 + w * 512);
    }
    __syncthreads();
#pragma unroll
    for (int kh = 0; kh < 2; ++kh) {
      bf16x8 af[4], bfr[4];
#pragma unroll
      for (int mi = 0; mi < 4; ++mi) {
        const int row = wm * 64 + mi * 16 + l15;
        const int ps = (kh * 4 + lq) ^ (row & 7);
        af[mi] = *(const bf16x8*)(As + row * 64 + ps * 8);
      }
#pragma unroll
      for (int ni = 0; ni < 4; ++ni) {
        const int row = wn * 64 + ni * 16 + l15;
        const int ps = (kh * 4 + lq) ^ (row & 7);
        bfr[ni] = *(const bf16x8*)(Bs + row * 64 + ps * 8);
      }
#pragma unroll
      for (int mi = 0; mi < 4; ++mi)
#pragma unroll
        for (int ni = 0; ni < 4; ++ni)
          acc[mi][ni] = __builtin_amdgcn_mfma_f32_16x16x32_bf16(af[mi], bfr[ni], acc[mi][ni], 0, 0, 0);
    }
    __syncthreads();
  }
#pragma unroll
  for (int mi = 0; mi < 4; ++mi)
#pragma unroll
    for (int ni = 0; ni < 4; ++ni) {
      const long gcol = colBase + wn * 64 + ni * 16 + l15;
      if (gcol >= Nvalid) continue;
      const float bv = bias ? bias[gcol] : 0.f;
#pragma unroll
      for (int r = 0; r < 4; ++r) {
        const long grow = rowBase + wm * 64 + mi * 16 + lq * 4 + r;
        const float v = acc[mi][ni][r] + bv;
        if (OUTF) outF[grow * ldo + gcol] = v;
        else      outB[grow * ldo + gcol] = f2bf(v);
      }
    }
}

// ============ K1: fused hp-GEMV + attention (1 block per batch row) ============
// Wt4 layout: Wt4[(k>>2)*2048 + j*4 + (k&3)] = W_h2h[j][k]
__global__ __launch_bounds__(512, 4) void attn_fused_k(
    const unsigned short* __restrict__ hrd, const unsigned short* __restrict__ Wt4,
    const float* __restrict__ b_h2h, const unsigned short* __restrict__ Hproj,
    const unsigned short* __restrict__ bH, const float* __restrict__ w_score,
    float* __restrict__ attn_map, unsigned short* __restrict__ ctx, int s) {
  const int b = blockIdx.x, tid = threadIdx.x;
  __shared__ float hs[512];
  __shared__ float hp_t[520];
  __shared__ float ws_t[520];
  __shared__ float e_s[64];
  __shared__ float csum[512];
  hs[tid] = bf2f(hrd[(long)b * 512 + tid]);
  ws_t[(tid & 7) * 65 + (tid >> 3)] = w_score[tid];
  __syncthreads();
  // GEMV: hp[tid] = b_h2h[tid] + sum_k hs[k] * W_h2h[tid][k]
  {
    float acc = b_h2h[tid];
    const unsigned short* wp = Wt4 + tid * 4;
#pragma unroll 4
    for (int k4 = 0; k4 < 128; ++k4) {
      const ushort4 wv = *(const ushort4*)(wp + k4 * 2048);
      const f32x4 hv = *(const f32x4*)(hs + k4 * 4);
      acc += bf2f(wv.x) * hv[0] + bf2f(wv.y) * hv[1]
           + bf2f(wv.z) * hv[2] + bf2f(wv.w) * hv[3];
    }
    hp_t[(tid & 7) * 65 + (tid >> 3)] = acc;
  }
  __syncthreads();
  // score: wave w8 handles 8 t-rows; lane l covers h = l*8..+8
  const int w8 = tid >> 6, l = tid & 63;
#pragma unroll
  for (int tt = 0; tt < 8; ++tt) {
    const int t = w8 * 8 + tt;
    const bf16x8 hv = *(const bf16x8*)(Hproj + ((long)b * 64 + t) * 512 + l * 8);
    float acc = 0.f;
#pragma unroll
    for (int j = 0; j < 8; ++j)
      acc += tanh_f(bf2f((unsigned short)hv[j]) + hp_t[j * 65 + l]) * ws_t[j * 65 + l];
    acc += __shfl_xor(acc, 1);
    acc += __shfl_xor(acc, 2);
    acc += __shfl_xor(acc, 4);
    acc += __shfl_xor(acc, 8);
    acc += __shfl_xor(acc, 16);
    acc += __shfl_xor(acc, 32);
    if (l == 0) e_s[t] = acc;
  }
  __syncthreads();
  if (tid < 64) {
    const float e = e_s[tid];
    float m = e;
    for (int off = 32; off; off >>= 1) m = fmaxf(m, __shfl_xor(m, off));
    const float p = __expf(e - m);
    float sum = p;
    for (int off = 32; off; off >>= 1) sum += __shfl_xor(sum, off);
    const float a = p / sum;
    e_s[tid] = a;
    attn_map[((long)b * 64 + tid) * NS_ + s] = a;
  }
  __syncthreads();
  const int half = tid >> 8, jj = tid & 255;
  float c0 = 0.f, c1 = 0.f;
  const unsigned* bhp = (const unsigned*)(bH + ((long)b * 64 + half * 32) * 512) + jj;
#pragma unroll 8
  for (int t = 0; t < 32; ++t) {
    const float a = e_s[half * 32 + t];
    const unsigned pv = bhp[(long)t * 256];
    c0 += a * bf2f((unsigned short)(pv & 0xffffu));
    c1 += a * bf2f((unsigned short)(pv >> 16));
  }
  if (half) { csum[jj * 2] = c0; csum[jj * 2 + 1] = c1; }
  __syncthreads();
  if (!half) {
    c0 += csum[jj * 2];
    c1 += csum[jj * 2 + 1];
    ((unsigned*)ctx)[(long)b * 256 + jj] = (unsigned)f2bf(c0) | ((unsigned)f2bf(c1) << 16);
  }
}

// ============ K2: gated fused — 16r x 64c tiles, grid (8,32) = 256 blocks ============
// wave w: which = w>>2 (0=f1lin, 1=z_ctx), nh = w&3 -> cols j0+nh*16..+16
__global__ __launch_bounds__(512, 4) void gated_fused_k(
    const unsigned short* __restrict__ ctx, const unsigned short* __restrict__ Wfz,
    const unsigned short* __restrict__ FZpre, const float* __restrict__ bf1,
    unsigned short* __restrict__ Ichar, float* __restrict__ Char_out, int s) {
  __shared__ float ls[2 * 16 * 65];
  const int tid = threadIdx.x, w = tid >> 6, l = tid & 63, l15 = l & 15, lq = l >> 4;
  const int b0 = blockIdx.y * 16, j0 = blockIdx.x * 64;
  const int which = w >> 2, nh = w & 3;
  f32x4 acc = {};
  const long arow = b0 + l15;
  const long gw = (long)(which ? 512 : 0) + j0 + nh * 16 + l15;
  for (int kt = 0; kt < 512; kt += 64) {
    const int k0 = kt + lq * 8, k1 = k0 + 32;
    const bf16x8 a0 = *(const bf16x8*)(ctx + arow * 512 + k0);
    const bf16x8 a1 = *(const bf16x8*)(ctx + arow * 512 + k1);
    const bf16x8 w0 = *(const bf16x8*)(Wfz + gw * 512 + k0);
    const bf16x8 w1 = *(const bf16x8*)(Wfz + gw * 512 + k1);
    acc = __builtin_amdgcn_mfma_f32_16x16x32_bf16(a0, w0, acc, 0, 0, 0);
    acc = __builtin_amdgcn_mfma_f32_16x16x32_bf16(a1, w1, acc, 0, 0, 0);
  }
#pragma unroll
  for (int r = 0; r < 4; ++r)
    ls[which * 1040 + (lq * 4 + r) * 65 + nh * 16 + l15] = acc[r];
  __syncthreads();
#pragma unroll
  for (int i = 0; i < 2; ++i) {
    const int e = tid + i * 512;
    const int r = e >> 6, c = e & 63;
    const long b = b0 + r;
    const int j = j0 + c;
    const float f1 = tanh_f(ls[r * 65 + c] + bf1[j]);
    const float zc = ls[1040 + r * 65 + c];
    const long pr = (b * NS_ + s) * 1024;
    const float f2 = tanh_f(bf2f(FZpre[pr + j]));
    const float z = sigm_f(zc + bf2f(FZpre[pr + 512 + j]));
    const float I = z * f1 + (1.f - z) * f2;
    Char_out[(b * NS_ + s) * 512 + j] = I;
    Ichar[b * 512 + j] = f2bf(I);
  }
}

// ============ K3: gates GEMM K=1280 — 32r x 32c tiles, grid (16,16) = 256 blocks ============
// wave w: g = w&3 (gate), mi = w>>2 (row-half); acc[2] over 2 col-subtiles
__global__ __launch_bounds__(512, 4) void gates_lstm_k(
    const unsigned short* __restrict__ Ichar, const unsigned short* __restrict__ embb,
    const unsigned short* __restrict__ hrd, const unsigned short* __restrict__ Wihh,
    const float* __restrict__ biasG, float* __restrict__ cbuf,
    float* __restrict__ hid_out, unsigned short* __restrict__ hwr, int s) {
  __shared__ float gs[4 * 32 * 33];
  const int tid = threadIdx.x, w = tid >> 6, l = tid & 63, l15 = l & 15, lq = l >> 4;
  const int b0 = blockIdx.y * 32, j0 = blockIdx.x * 32;
  const int g = w & 3, mi = w >> 2;
  const long arow = b0 + mi * 16 + l15;
  f32x4 acc[2] = {};
  for (int kt = 0; kt < 1280; kt += 64) {
    const int k0 = kt + lq * 8, k1 = k0 + 32;
    bf16x8 a0, a1, b0r[2], b1r[2];
    if (kt < 512) {
      a0 = *(const bf16x8*)(Ichar + arow * 512 + k0);
      a1 = *(const bf16x8*)(Ichar + arow * 512 + k1);
    } else if (kt < 768) {
      a0 = *(const bf16x8*)(embb + (arow * NS_ + s) * 256 + (k0 - 512));
      a1 = *(const bf16x8*)(embb + (arow * NS_ + s) * 256 + (k1 - 512));
    } else {
      a0 = *(const bf16x8*)(hrd + arow * 512 + (k0 - 768));
      a1 = *(const bf16x8*)(hrd + arow * 512 + (k1 - 768));
    }
#pragma unroll
    for (int ni = 0; ni < 2; ++ni) {
      const long wrow = (long)g * 512 + j0 + ni * 16 + l15;
      b0r[ni] = *(const bf16x8*)(Wihh + wrow * 1280 + k0);
      b1r[ni] = *(const bf16x8*)(Wihh + wrow * 1280 + k1);
    }
#pragma unroll
    for (int ni = 0; ni < 2; ++ni) {
      acc[ni] = __builtin_amdgcn_mfma_f32_16x16x32_bf16(a0, b0r[ni], acc[ni], 0, 0, 0);
      acc[ni] = __builtin_amdgcn_mfma_f32_16x16x32_bf16(a1, b1r[ni], acc[ni], 0, 0, 0);
    }
  }
#pragma unroll
  for (int ni = 0; ni < 2; ++ni)
#pragma unroll
    for (int r = 0; r < 4; ++r) {
      const int rl = mi * 16 + lq * 4 + r;
      const int cl = ni * 16 + l15;
      gs[(g * 32 + rl) * 33 + cl] = acc[ni][r];
    }
  __syncthreads();
#pragma unroll
  for (int i = 0; i < 2; ++i) {
    const int e = tid + i * 512;
    const int r = e >> 5, c = e & 31;
    const long b = b0 + r;
    const int j = j0 + c;
    const float ig = sigm_f(gs[(0 * 32 + r) * 33 + c] + biasG[j]);
    const float fg = sigm_f(gs[(1 * 32 + r) * 33 + c] + biasG[512 + j]);
    const float gg = tanh_f(gs[(2 * 32 + r) * 33 + c] + biasG[1024 + j]);
    const float og = sigm_f(gs[(3 * 32 + r) * 33 + c] + biasG[1536 + j]);
    const float cn = fg * cbuf[b * 512 + j] + ig * gg;
    cbuf[b * 512 + j] = cn;
    const float h = og * tanh_f(cn);
    hid_out[(b * NS_ + s) * 512 + j] = h;
    hwr[b * 512 + j] = f2bf(h);
  }
}

// ============ final probs GEMM ============
__global__ __launch_bounds__(256) void probs_k(
    const float* __restrict__ Af, const unsigned short* __restrict__ Wg,
    const float* __restrict__ bias, float* __restrict__ outp) {
  const int tid = threadIdx.x, w = tid >> 6, l = tid & 63, l15 = l & 15, lq = l >> 4;
  const long mrow = (long)blockIdx.y * 64 + w * 16 + l15;
  const int nbase = blockIdx.x * 64;
  f32x4 acc[4] = {};
  for (int kt = 0; kt < 512; kt += 32) {
    const int k = kt + lq * 8;
    const float4 av0 = *(const float4*)(Af + mrow * 512 + k);
    const float4 av1 = *(const float4*)(Af + mrow * 512 + k + 4);
    bf16x8 a;
    a[0] = (short)f2bf(av0.x); a[1] = (short)f2bf(av0.y);
    a[2] = (short)f2bf(av0.z); a[3] = (short)f2bf(av0.w);
    a[4] = (short)f2bf(av1.x); a[5] = (short)f2bf(av1.y);
    a[6] = (short)f2bf(av1.z); a[7] = (short)f2bf(av1.w);
#pragma unroll
    for (int nb = 0; nb < 4; ++nb) {
      const bf16x8 b = *(const bf16x8*)(Wg + (long)(nbase + nb * 16 + l15) * 512 + k);
      acc[nb] = __builtin_amdgcn_mfma_f32_16x16x32_bf16(a, b, acc[nb], 0, 0, 0);
    }
  }
#pragma unroll
  for (int nb = 0; nb < 4; ++nb) {
    const int colg = nbase + nb * 16 + l15;
    if (colg >= NCLS_) continue;
    const float bv = bias[colg];
#pragma unroll
    for (int r = 0; r < 4; ++r) {
      const long rowg = (long)blockIdx.y * 64 + w * 16 + lq * 4 + r;
      outp[rowg * NCLS_ + colg] = acc[nb][r] + bv;
    }
  }
}

// ============ prologue helpers ============
__global__ void cvt_f32_bf16_k(const float* __restrict__ in, unsigned short* __restrict__ out, long n) {
  const long i = ((long)blockIdx.x * 256 + threadIdx.x) * 4;
  if (i + 4 <= n) {
    const float4 v = *(const float4*)(in + i);
    ushort4 o;
    o.x = f2bf(v.x); o.y = f2bf(v.y); o.z = f2bf(v.z); o.w = f2bf(v.w);
    *(ushort4*)(out + i) = o;
  }
}

__global__ void embed_k(const float* __restrict__ emb_table, const int* __restrict__ text,
                        unsigned short* __restrict__ out) {
  const int bs = blockIdx.x, j = threadIdx.x;
  const int t = text[bs];
  out[(long)bs * 256 + j] = f2bf(emb_table[(long)t * 256 + j]);
}

// Wt4[(k>>2)*2048 + j*4 + (k&3)] = W_h2h[j][k]
__global__ void pack_Wt4_k(const float* __restrict__ W, unsigned short* __restrict__ out) {
  const long idx = (long)blockIdx.x * 256 + threadIdx.x;  // 262144
  const int j = (int)(idx >> 9), k = (int)(idx & 511);
  out[((long)(k >> 2) * 2048) + j * 4 + (k & 3)] = f2bf(W[idx]);
}

// Wihh [2048,1280]: cols 0..767 = W_ih, cols 768..1279 = W_hh
__global__ void pack_Wihh_k(const float* __restrict__ W_ih, const float* __restrict__ W_hh,
                            unsigned short* __restrict__ out) {
  const long idx = (long)blockIdx.x * 256 + threadIdx.x;  // 2048*1280
  const int row = (int)(idx / 1280), c = (int)(idx % 1280);
  const float v = (c < 768) ? W_ih[(long)row * 768 + c] : W_hh[(long)row * 512 + (c - 768)];
  out[idx] = f2bf(v);
}

__global__ void pack_wfz_k(const float* __restrict__ Wf, const float* __restrict__ Wz, int zoff,
                           unsigned short* __restrict__ out) {
  const long idx = (long)blockIdx.x * 256 + threadIdx.x;
  const int row = (int)(idx >> 9), k = (int)(idx & 511);
  const float v = (row < 512) ? Wf[(long)row * 512 + k]
                              : Wz[(long)(row - 512) * 1024 + zoff + k];
  out[idx] = f2bf(v);
}

__global__ void pack_Wgen_k(const float* __restrict__ W_gen, unsigned short* __restrict__ out) {
  const long idx = (long)blockIdx.x * 256 + threadIdx.x;  // 128*512
  const int row = (int)(idx >> 9), k = (int)(idx & 511);
  out[idx] = (row < NCLS_) ? f2bf(W_gen[(long)row * 512 + k]) : (unsigned short)0;
}

// biasG [2048] = b_ih + b_hh ; biasFZ [1024] = [bf2 | bz]
__global__ void pack_bias_k(const float* __restrict__ b_ih, const float* __restrict__ b_hh,
                            const float* __restrict__ bf2, const float* __restrict__ bz,
                            float* __restrict__ biasG, float* __restrict__ biasFZ) {
  const int i = blockIdx.x * 256 + threadIdx.x;  // 3072
  if (i < 2048) {
    biasG[i] = b_ih[i] + b_hh[i];
  } else {
    const int j = i - 2048;
    biasFZ[j] = (j < 512) ? bf2[j] : bz[j - 512];
  }
}

extern "C" void kernel_launch(void* const* d_in, const int* in_sizes, int n_in,
                              void* d_out, int out_size, void* d_ws, size_t ws_size,
                              hipStream_t stream) {
  (void)in_sizes; (void)n_in; (void)out_size; (void)ws_size;
  const float* batch_H  = (const float*)d_in[0];
  const float* AS       = (const float*)d_in[1];
  const int*   text     = (const int*)d_in[2];
  const float* W_i2h    = (const float*)d_in[3];
  const float* W_h2h    = (const float*)d_in[4];
  const float* b_h2h    = (const float*)d_in[5];
  const float* w_score  = (const float*)d_in[6];
  const float* W_ih     = (const float*)d_in[7];
  const float* W_hh     = (const float*)d_in[8];
  const float* b_ih     = (const float*)d_in[9];
  const float* b_hh     = (const float*)d_in[10];
  const float* Wf1      = (const float*)d_in[11];
  const float* bf1      = (const float*)d_in[12];
  const float* Wf2      = (const float*)d_in[13];
  const float* bf2      = (const float*)d_in[14];
  const float* Wz       = (const float*)d_in[15];
  const float* bz       = (const float*)d_in[16];
  const float* W_gen    = (const float*)d_in[17];
  const float* b_gen    = (const float*)d_in[18];
  const float* emb_tab  = (const float*)d_in[19];

  float* out = (float*)d_out;
  float* out_probs = out;                       // [B,NS,NCLS]
  float* out_attn  = out + 1291264;             // [B,T,NS]
  float* out_hid   = out + 2143232;             // [B,NS,H]
  float* out_char  = out + 8958976;             // [B,NS,H]

  char* wsp = (char*)d_ws;
  auto alloc = [&](size_t bytes) { char* p = wsp; wsp += (bytes + 255) & ~(size_t)255; return p; };
  unsigned short* bH    = (unsigned short*)alloc(33554432);  // [B,T,C] bf16
  unsigned short* Hproj = (unsigned short*)alloc(33554432);  // [B,T,H] bf16
  unsigned short* ASb   = (unsigned short*)alloc(13631488);  // [B*NS,512] bf16 (prologue only)
  unsigned short* embb  = (unsigned short*)alloc(6815744);   // [B,NS,NEMB] bf16
  unsigned short* FZpre = (unsigned short*)alloc(27262976);  // [B*NS,1024] bf16
  unsigned short* Wt4   = (unsigned short*)alloc(524288);    // [128][512][4] packed W_h2h
  unsigned short* Wfz   = (unsigned short*)alloc(1048576);   // [1024,512]  (Wf1 | Wz-left)
  unsigned short* Wfz2  = (unsigned short*)alloc(1048576);   // [1024,512]  (Wf2 | Wz-right)
  unsigned short* Wihh  = (unsigned short*)alloc(5242880);   // [2048,1280]
  unsigned short* Wgenb = (unsigned short*)alloc(131072);    // [128,512]
  unsigned short* Wi2hb = (unsigned short*)alloc(524288);    // [512,512]
  float* biasG          = (float*)alloc(8192);               // [2048]
  float* biasFZ         = (float*)alloc(4096);               // [1024]
  // ---- aliased into ASb (dead after FZpre GEMM) ----
  char* ab = (char*)ASb;
  unsigned short* ctx   = (unsigned short*)(ab);             // [B,512] bf16 (524288)
  unsigned short* Ichar = (unsigned short*)(ab + 524288);    // [B,512] bf16 (524288)
  float* cbuf           = (float*)(ab + 1048576);            // [B,512] f32 (1048576)
  unsigned short* hbuf  = (unsigned short*)(ab + 2097152);   // 2x [B,512] bf16 (1048576)

  // -------- prologue --------
  cvt_f32_bf16_k<<<dim3(16384), dim3(256), 0, stream>>>(batch_H, bH, 16777216);
  cvt_f32_bf16_k<<<dim3(6656), dim3(256), 0, stream>>>(AS, ASb, 6815744);
  cvt_f32_bf16_k<<<dim3(256), dim3(256), 0, stream>>>(W_i2h, Wi2hb, 262144);
  embed_k<<<dim3(13312), dim3(256), 0, stream>>>(emb_tab, text, embb);
  pack_Wt4_k<<<dim3(1024), dim3(256), 0, stream>>>(W_h2h, Wt4);
  pack_Wihh_k<<<dim3(10240), dim3(256), 0, stream>>>(W_ih, W_hh, Wihh);
  pack_wfz_k<<<dim3(2048), dim3(256), 0, stream>>>(Wf1, Wz, 0, Wfz);
  pack_wfz_k<<<dim3(2048), dim3(256), 0, stream>>>(Wf2, Wz, 512, Wfz2);
  pack_Wgen_k<<<dim3(256), dim3(256), 0, stream>>>(W_gen, Wgenb);
  pack_bias_k<<<dim3(12), dim3(256), 0, stream>>>(b_ih, b_hh, bf2, bz, biasG, biasFZ);

  // H_proj = batch_H @ W_i2h^T  (M=32768, N=512, K=512) -> bf16
  gemm_tiled_k<false><<<dim3(4, 256), dim3(256), 0, stream>>>(
      bH, Wi2hb, nullptr, nullptr, Hproj, 512, 512, 512);

  // FZpre = AS @ [Wf2 | Wz-right]^T + [bf2 | bz]  (M=13312, N=1024, K=512) -> bf16
  gemm_tiled_k<false><<<dim3(8, 104), dim3(256), 0, stream>>>(
      ASb, Wfz2, biasFZ, nullptr, FZpre, 512, 1024, 1024);

  // ASb region dead -> init aliased state buffers
  hipMemsetAsync(cbuf, 0, 1048576, stream);
  hipMemsetAsync(hbuf, 0, 1048576, stream);

  // -------- 26-step scan: 3 kernels per step --------
  for (int s = 0; s < NS_; ++s) {
    unsigned short* hrd = hbuf + (s & 1) * 262144;
    unsigned short* hwr = hbuf + ((s + 1) & 1) * 262144;
    attn_fused_k<<<dim3(512), dim3(512), 0, stream>>>(
        hrd, Wt4, b_h2h, Hproj, bH, w_score, out_attn, ctx, s);
    gated_fused_k<<<dim3(8, 32), dim3(512), 0, stream>>>(
        ctx, Wfz, FZpre, bf1, Ichar, out_char, s);
    gates_lstm_k<<<dim3(16, 16), dim3(512), 0, stream>>>(
        Ichar, embb, hrd, Wihh, biasG, cbuf, out_hid, hwr, s);
  }

  // probs = out_hid @ W_gen^T + b_gen
  probs_k<<<dim3(2, 208), dim3(256), 0, stream>>>(out_hid, Wgenb, b_gen, out_probs);
}